// Round 2
// baseline (10054.810 us; speedup 1.0000x reference)
//
#include <hip/hip_runtime.h>
#include <math.h>

#define H 4
#define D 32
#define C 128

typedef unsigned short ushort_t;

// ---------- helpers ----------
__device__ __forceinline__ float bf2f(ushort_t u) {
    return __uint_as_float(((unsigned)u) << 16);
}
__device__ __forceinline__ ushort_t f2bf(float f) {
    unsigned u = __float_as_uint(f);
    u += 0x7fffu + ((u >> 16) & 1u);
    return (ushort_t)(u >> 16);
}
__device__ __forceinline__ void unpack2(unsigned w, float& a, float& b) {
    a = __uint_as_float(w << 16);
    b = __uint_as_float(w & 0xffff0000u);
}
__device__ __forceinline__ float dotbf(unsigned a, unsigned b) {
    float a0, a1, b0, b1;
    unpack2(a, a0, a1); unpack2(b, b0, b1);
    return a0 * b0 + a1 * b1;
}
__device__ __forceinline__ float gelu_t(float x) {
    float x3 = x * x * x;
    float t = tanhf(0.7978845608028654f * (x + 0.044715f * x3));
    return 0.5f * x * (1.0f + t);
}

// ---------- diag: encode ws_size into output if workspace too small ----------
__global__ void diag_fill(float* out, int n, float v) {
    int i = blockIdx.x * 256 + threadIdx.x;
    if (i < n) out[i] = v;
}

// ---------- fused relation weights: W' = W @ blockdiag(rel), b' = b @ blockdiag(rel) ----------
__global__ void fuse_weights(const float* __restrict__ kW, const float* __restrict__ kb,
                             const float* __restrict__ vW, const float* __restrict__ vb,
                             const float* __restrict__ relA, const float* __restrict__ relM,
                             float* __restrict__ fw)
{
    int bid = blockIdx.x;      // 0..11
    int le = bid >> 1;         // 0..5  (l*3+e)
    int which = bid & 1;       // 0 = k/relA, 1 = v/relM
    int l = le / 3, e = le % 3;
    const int est[3] = {1, 0, 0};
    int st = est[e];
    const float* Wsrc = (which ? vW : kW) + (size_t)(l * 2 + st) * C * C;
    const float* bsrc = (which ? vb : kb) + (size_t)(l * 2 + st) * C;
    const float* rel  = (which ? relM : relA) + (size_t)(l * 3 + e) * H * D * D;
    float* out = fw + (size_t)(le * 2 + which) * (C * C + C);

    __shared__ float rsh[H * D * D];  // 16KB
    for (int i = threadIdx.x; i < H * D * D; i += 256) rsh[i] = rel[i];
    __syncthreads();

    for (int i = threadIdx.x; i < C * C; i += 256) {
        int c = i >> 7, hf = i & 127, h = hf >> 5, f = hf & 31;
        float acc = 0.f;
        #pragma unroll
        for (int d = 0; d < D; ++d)
            acc += Wsrc[c * C + h * D + d] * rsh[h * D * D + d * D + f];
        out[i] = acc;
    }
    for (int i = threadIdx.x; i < C; i += 256) {
        int h = i >> 5, f = i & 31;
        float acc = 0.f;
        #pragma unroll
        for (int d = 0; d < D; ++d)
            acc += bsrc[h * D + d] * rsh[h * D * D + d * D + f];
        out[C * C + i] = acc;
    }
}

// ---------- generic [N,128] @ [128,128] + bias ----------
// INBF/OUTBF: 0 = f32 buffer, 1 = bf16 buffer
// PRE:  0 none, 1 gelu(x) on input
// POST: 0 none, 1 relu, 2 blend: y = g*y + (1-g)*Old,  g = sigmoid(*skipp)
template <int INBF, int OUTBF, int PRE, int POST>
__global__ __launch_bounds__(256) void gemm128(
    const void* __restrict__ Xv, const float* __restrict__ W,
    const float* __restrict__ bias, void* __restrict__ Yv,
    const void* __restrict__ Oldv, const float* __restrict__ skipp, int N)
{
    __shared__ float Wsh[C * C];    // 64KB
    __shared__ float Xsh[64 * C];   // 32KB
    const int tid = threadIdx.x;

    {
        const float4* W4 = (const float4*)W;
        float4* Wsh4 = (float4*)Wsh;
        for (int i = tid; i < C * C / 4; i += 256) Wsh4[i] = W4[i];
    }
    const int rbase = (tid >> 5) * 8;   // 8 rows per thread
    const int cbase = (tid & 31) * 4;   // 4 cols per thread
    const float4 bb = *(const float4*)(bias + cbase);
    float g = 0.f;
    if (POST == 2) g = 1.0f / (1.0f + __expf(-skipp[0]));

    const int tiles = (N + 63) >> 6;
    for (int t = blockIdx.x; t < tiles; t += gridDim.x) {
        const int row0 = t << 6;
        __syncthreads();  // protect Xsh reuse (and cover W load on first iter)
        for (int i = tid; i < 64 * 32; i += 256) {
            int r = i >> 5, q4 = i & 31;
            int grow = row0 + r;
            float4 v = make_float4(0.f, 0.f, 0.f, 0.f);
            if (grow < N) {
                if (INBF) {
                    ushort4 u = *(const ushort4*)((const ushort_t*)Xv + (size_t)grow * C + q4 * 4);
                    v.x = bf2f(u.x); v.y = bf2f(u.y); v.z = bf2f(u.z); v.w = bf2f(u.w);
                } else {
                    v = ((const float4*)Xv)[(size_t)grow * 32 + q4];
                }
                if (PRE == 1) {
                    v.x = gelu_t(v.x); v.y = gelu_t(v.y);
                    v.z = gelu_t(v.z); v.w = gelu_t(v.w);
                }
            }
            *(float4*)&Xsh[r * C + q4 * 4] = v;
        }
        __syncthreads();

        float4 acc[8];
        #pragma unroll
        for (int r = 0; r < 8; ++r) acc[r] = make_float4(0.f, 0.f, 0.f, 0.f);

        for (int k = 0; k < C; k += 4) {
            float4 w0 = *(float4*)&Wsh[(k + 0) * C + cbase];
            float4 w1 = *(float4*)&Wsh[(k + 1) * C + cbase];
            float4 w2 = *(float4*)&Wsh[(k + 2) * C + cbase];
            float4 w3 = *(float4*)&Wsh[(k + 3) * C + cbase];
            #pragma unroll
            for (int r = 0; r < 8; ++r) {
                float4 xv = *(float4*)&Xsh[(rbase + r) * C + k];
                acc[r].x += xv.x * w0.x + xv.y * w1.x + xv.z * w2.x + xv.w * w3.x;
                acc[r].y += xv.x * w0.y + xv.y * w1.y + xv.z * w2.y + xv.w * w3.y;
                acc[r].z += xv.x * w0.z + xv.y * w1.z + xv.z * w2.z + xv.w * w3.z;
                acc[r].w += xv.x * w0.w + xv.y * w1.w + xv.z * w2.w + xv.w * w3.w;
            }
        }

        #pragma unroll
        for (int r = 0; r < 8; ++r) {
            int grow = row0 + rbase + r;
            if (grow < N) {
                float4 y;
                y.x = acc[r].x + bb.x; y.y = acc[r].y + bb.y;
                y.z = acc[r].z + bb.z; y.w = acc[r].w + bb.w;
                if (POST == 1) {
                    y.x = fmaxf(y.x, 0.f); y.y = fmaxf(y.y, 0.f);
                    y.z = fmaxf(y.z, 0.f); y.w = fmaxf(y.w, 0.f);
                }
                if (POST == 2) {
                    float4 o;
                    if (OUTBF) {
                        ushort4 u = *(const ushort4*)((const ushort_t*)Oldv + (size_t)grow * C + cbase);
                        o = make_float4(bf2f(u.x), bf2f(u.y), bf2f(u.z), bf2f(u.w));
                    } else {
                        o = *(const float4*)((const float*)Oldv + (size_t)grow * C + cbase);
                    }
                    y.x = g * y.x + (1.f - g) * o.x;
                    y.y = g * y.y + (1.f - g) * o.y;
                    y.z = g * y.z + (1.f - g) * o.z;
                    y.w = g * y.w + (1.f - g) * o.w;
                }
                if (OUTBF) {
                    ushort4 s4 = make_ushort4(f2bf(y.x), f2bf(y.y), f2bf(y.z), f2bf(y.w));
                    *(ushort4*)((ushort_t*)Yv + (size_t)grow * C + cbase) = s4;
                } else {
                    *(float4*)((float*)Yv + (size_t)grow * C + cbase) = y;
                }
            }
        }
    }
}

// ---------- edge pass A: alpha + exp-sum denominator (no max shift; alpha ~ N(0,1)) ----------
template <int BF>
__global__ void edge_alpha(const int* __restrict__ ei, int E,
                           const void* __restrict__ kp, const void* __restrict__ q,
                           const float* __restrict__ relP, float* __restrict__ alpha,
                           float* __restrict__ denom)
{
    int gid = blockIdx.x * 256 + threadIdx.x;
    if (gid >= E * H) return;
    int e = gid >> 2, h = gid & 3;
    int s = ei[e], d = ei[E + e];
    float acc = 0.f;
    if (BF) {
        const uint4* kr = (const uint4*)((const ushort_t*)kp + (size_t)s * C + h * D);
        const uint4* qr = (const uint4*)((const ushort_t*)q + (size_t)d * C + h * D);
        #pragma unroll
        for (int i = 0; i < 4; ++i) {
            uint4 a = kr[i], b = qr[i];
            acc += dotbf(a.x, b.x) + dotbf(a.y, b.y) + dotbf(a.z, b.z) + dotbf(a.w, b.w);
        }
    } else {
        const float4* kr = (const float4*)((const float*)kp + (size_t)s * C + h * D);
        const float4* qr = (const float4*)((const float*)q + (size_t)d * C + h * D);
        #pragma unroll
        for (int i = 0; i < 8; ++i) {
            float4 a = kr[i], b = qr[i];
            acc += a.x * b.x + a.y * b.y + a.z * b.z + a.w * b.w;
        }
    }
    float al = acc * relP[h] * 0.17677669529663687f;  // 1/sqrt(32)
    alpha[gid] = al;
    unsafeAtomicAdd(denom + (size_t)d * H + h, __expf(al));
}

// ---------- edge pass B: normalized weighted scatter of v' ----------
template <int BF>
__global__ void edge_scatter(const int* __restrict__ ei, int E,
                             const void* __restrict__ vp, const float* __restrict__ alpha,
                             const float* __restrict__ denom, float* __restrict__ agg)
{
    int gid = blockIdx.x * 256 + threadIdx.x;
    if (BF) {
        if (gid >= E * 16) return;
        int e = gid >> 4, j = gid & 15, h = j >> 2;   // 8 elems per thread
        int s = ei[e], d = ei[E + e];
        float att = __expf(alpha[(size_t)e * H + h]) / (denom[(size_t)d * H + h] + 1e-16f);
        uint4 u = ((const uint4*)((const ushort_t*)vp + (size_t)s * C))[j];
        float* ag = agg + (size_t)d * C + j * 8;
        float a0, a1;
        unpack2(u.x, a0, a1); unsafeAtomicAdd(ag + 0, att * a0); unsafeAtomicAdd(ag + 1, att * a1);
        unpack2(u.y, a0, a1); unsafeAtomicAdd(ag + 2, att * a0); unsafeAtomicAdd(ag + 3, att * a1);
        unpack2(u.z, a0, a1); unsafeAtomicAdd(ag + 4, att * a0); unsafeAtomicAdd(ag + 5, att * a1);
        unpack2(u.w, a0, a1); unsafeAtomicAdd(ag + 6, att * a0); unsafeAtomicAdd(ag + 7, att * a1);
    } else {
        if (gid >= E * 32) return;
        int e = gid >> 5, j = gid & 31, h = j >> 3;   // 4 elems per thread
        int s = ei[e], d = ei[E + e];
        float att = __expf(alpha[(size_t)e * H + h]) / (denom[(size_t)d * H + h] + 1e-16f);
        float4 v = ((const float4*)((const float*)vp + (size_t)s * C))[j];
        float* ag = agg + (size_t)d * C + j * 4;
        unsafeAtomicAdd(ag + 0, att * v.x);
        unsafeAtomicAdd(ag + 1, att * v.y);
        unsafeAtomicAdd(ag + 2, att * v.z);
        unsafeAtomicAdd(ag + 3, att * v.w);
    }
}

// ---------- final: gather last visit per patient, @ linW + linb ----------
template <int BF>
__global__ void final_lin(const void* __restrict__ xs0, const int* __restrict__ slices,
                          const float* __restrict__ Wl, const float* __restrict__ bl,
                          float* __restrict__ out)
{
    __shared__ float xr[C];
    int b = blockIdx.x, o = threadIdx.x;
    int row = slices[b + 1] - 1;
    if (BF) xr[o] = bf2f(((const ushort_t*)xs0)[(size_t)row * C + o]);
    else    xr[o] = ((const float*)xs0)[(size_t)row * C + o];
    __syncthreads();
    float acc = bl[o];
    #pragma unroll 4
    for (int c = 0; c < C; ++c) acc += xr[c] * Wl[c * C + o];
    out[(size_t)b * C + o] = acc;
}

// ---------- workspace plan ----------
struct WsPlan {
    size_t xs0, xs1, qbuf, kvbuf, aggV, aggC, alpha, denom, fw, total;
};
static WsPlan make_plan(size_t NV, size_t NC, size_t NN, size_t Emax, int bf) {
    size_t es = bf ? 2 : 4;
    WsPlan p; size_t off = 0;
    auto A = [&](size_t bytes) { size_t c = off; off += (bytes + 255) & ~(size_t)255; return c; };
    p.xs0   = A(NV * C * es);
    p.xs1   = A(NC * C * es);
    p.qbuf  = A(NN * C * es);
    p.kvbuf = A(NN * C * es);
    p.aggV  = A(NV * C * 4);
    p.aggC  = A(NC * C * 4);
    p.alpha = A(Emax * H * 4);
    p.denom = A(NN * H * 4);
    p.fw    = A((size_t)12 * (C * C + C) * 4);
    p.total = off;
    return p;
}

extern "C" void kernel_launch(void* const* d_in, const int* in_sizes, int n_in,
                              void* d_out, int out_size, void* d_ws, size_t ws_size,
                              hipStream_t stream)
{
    (void)n_in;
    const float* x_visit = (const float*)d_in[0];
    const float* x_code  = (const float*)d_in[1];
    const int* edge_in   = (const int*)d_in[2];
    const int* edge_has  = (const int*)d_in[3];
    const int* edge_next = (const int*)d_in[4];
    const int* slices    = (const int*)d_in[5];
    const float* lin0_W  = (const float*)d_in[6];
    const float* lin0_b  = (const float*)d_in[7];
    const float* kW  = (const float*)d_in[8];
    const float* kb  = (const float*)d_in[9];
    const float* qW  = (const float*)d_in[10];
    const float* qb  = (const float*)d_in[11];
    const float* vW  = (const float*)d_in[12];
    const float* vb  = (const float*)d_in[13];
    const float* aW  = (const float*)d_in[14];
    const float* ab  = (const float*)d_in[15];
    const float* skip = (const float*)d_in[16];
    const float* relA = (const float*)d_in[17];
    const float* relM = (const float*)d_in[18];
    const float* relP = (const float*)d_in[19];
    const float* linW = (const float*)d_in[20];
    const float* linb = (const float*)d_in[21];

    const int NV = in_sizes[0] / C;
    const int NC = in_sizes[1] / C;
    const int NN = NV > NC ? NV : NC;
    const int E0 = in_sizes[2] / 2, E1 = in_sizes[3] / 2, E2 = in_sizes[4] / 2;
    int Emax = E0 > E1 ? E0 : E1; if (E2 > Emax) Emax = E2;
    const int B = in_sizes[5] - 1;

    WsPlan pf = make_plan(NV, NC, NN, Emax, 0);
    WsPlan pb = make_plan(NV, NC, NN, Emax, 1);
    int mode;
    WsPlan p;
    if (ws_size >= pf.total)      { mode = 0; p = pf; }
    else if (ws_size >= pb.total) { mode = 1; p = pb; }
    else {
        // not enough scratch: encode ws_size (GB) into output for diagnosis
        float v = 10.0f + (float)((double)ws_size * 1e-9);
        diag_fill<<<(out_size + 255) / 256, 256, 0, stream>>>((float*)d_out, out_size, v);
        return;
    }

    char* base = (char*)d_ws;
    void* xs0   = base + p.xs0;
    void* xs1   = base + p.xs1;
    void* qbuf  = base + p.qbuf;
    void* kvbuf = base + p.kvbuf;
    float* aggV  = (float*)(base + p.aggV);
    float* aggC  = (float*)(base + p.aggC);
    float* alpha = (float*)(base + p.alpha);
    float* denom = (float*)(base + p.denom);
    float* fw    = (float*)(base + p.fw);

    fuse_weights<<<12, 256, 0, stream>>>(kW, kb, vW, vb, relA, relM, fw);

    auto grid_of = [](int N) { int t = (N + 63) / 64; return dim3((unsigned)(t < 1024 ? t : 1024)); };

    // input projection + relu
    if (mode == 0) {
        gemm128<0, 0, 0, 1><<<grid_of(NV), 256, 0, stream>>>(x_visit, lin0_W, lin0_b, xs0, nullptr, nullptr, NV);
        gemm128<0, 0, 0, 1><<<grid_of(NC), 256, 0, stream>>>(x_code, lin0_W + C * C, lin0_b + C, xs1, nullptr, nullptr, NC);
    } else {
        gemm128<0, 1, 0, 1><<<grid_of(NV), 256, 0, stream>>>(x_visit, lin0_W, lin0_b, xs0, nullptr, nullptr, NV);
        gemm128<0, 1, 0, 1><<<grid_of(NC), 256, 0, stream>>>(x_code, lin0_W + C * C, lin0_b + C, xs1, nullptr, nullptr, NC);
    }

    const int est[3] = {1, 0, 0}, edt[3] = {0, 1, 0};
    const int* eptr[3] = {edge_in, edge_has, edge_next};
    const int Ecnt[3] = {E0, E1, E2};

    for (int l = 0; l < 2; ++l) {
        hipMemsetAsync(aggV, 0, (size_t)NV * C * 4, stream);
        hipMemsetAsync(aggC, 0, (size_t)NC * C * 4, stream);

        for (int e = 0; e < 3; ++e) {
            const int st = est[e], dt = edt[e];
            const void* xsrc = st ? xs1 : xs0;
            const void* xdst = dt ? xs1 : xs0;
            const int Ns = st ? NC : NV;
            const int Nd = dt ? NC : NV;
            const int E = Ecnt[e];
            const float* fk = fw + (size_t)((l * 3 + e) * 2 + 0) * (C * C + C);
            const float* fv = fw + (size_t)((l * 3 + e) * 2 + 1) * (C * C + C);
            const float* qWp = qW + (size_t)(l * 2 + dt) * C * C;
            const float* qbp = qb + (size_t)(l * 2 + dt) * C;

            // q (dst-type), then k' (src-type through fused relA weights)
            if (mode == 0) {
                gemm128<0, 0, 0, 0><<<grid_of(Nd), 256, 0, stream>>>(xdst, qWp, qbp, qbuf, nullptr, nullptr, Nd);
                gemm128<0, 0, 0, 0><<<grid_of(Ns), 256, 0, stream>>>(xsrc, fk, fk + C * C, kvbuf, nullptr, nullptr, Ns);
            } else {
                gemm128<1, 1, 0, 0><<<grid_of(Nd), 256, 0, stream>>>(xdst, qWp, qbp, qbuf, nullptr, nullptr, Nd);
                gemm128<1, 1, 0, 0><<<grid_of(Ns), 256, 0, stream>>>(xsrc, fk, fk + C * C, kvbuf, nullptr, nullptr, Ns);
            }

            hipMemsetAsync(denom, 0, (size_t)Nd * H * 4, stream);
            int nA = E * H;
            const float* rp = relP + (size_t)(l * 3 + e) * H;
            if (mode == 0)
                edge_alpha<0><<<(nA + 255) / 256, 256, 0, stream>>>(eptr[e], E, kvbuf, qbuf, rp, alpha, denom);
            else
                edge_alpha<1><<<(nA + 255) / 256, 256, 0, stream>>>(eptr[e], E, kvbuf, qbuf, rp, alpha, denom);

            // v' overwrites kvbuf (k' no longer needed)
            if (mode == 0)
                gemm128<0, 0, 0, 0><<<grid_of(Ns), 256, 0, stream>>>(xsrc, fv, fv + C * C, kvbuf, nullptr, nullptr, Ns);
            else
                gemm128<1, 1, 0, 0><<<grid_of(Ns), 256, 0, stream>>>(xsrc, fv, fv + C * C, kvbuf, nullptr, nullptr, Ns);

            float* agg_d = dt ? aggC : aggV;
            if (mode == 0) {
                int nB = E * 32;
                edge_scatter<0><<<(nB + 255) / 256, 256, 0, stream>>>(eptr[e], E, kvbuf, alpha, denom, agg_d);
            } else {
                int nB = E * 16;
                edge_scatter<1><<<(nB + 255) / 256, 256, 0, stream>>>(eptr[e], E, kvbuf, alpha, denom, agg_d);
            }
        }

        // node update: x = g*(gelu(agg) @ aW + ab) + (1-g)*x
        const float* aW0 = aW + (size_t)(l * 2 + 0) * C * C;
        const float* aW1 = aW + (size_t)(l * 2 + 1) * C * C;
        if (mode == 0) {
            gemm128<0, 0, 1, 2><<<grid_of(NV), 256, 0, stream>>>(aggV, aW0, ab + (l * 2 + 0) * C, xs0, xs0, skip + (l * 2 + 0), NV);
            gemm128<0, 0, 1, 2><<<grid_of(NC), 256, 0, stream>>>(aggC, aW1, ab + (l * 2 + 1) * C, xs1, xs1, skip + (l * 2 + 1), NC);
        } else {
            gemm128<0, 1, 1, 2><<<grid_of(NV), 256, 0, stream>>>(aggV, aW0, ab + (l * 2 + 0) * C, xs0, xs0, skip + (l * 2 + 0), NV);
            gemm128<0, 1, 1, 2><<<grid_of(NC), 256, 0, stream>>>(aggC, aW1, ab + (l * 2 + 1) * C, xs1, xs1, skip + (l * 2 + 1), NC);
        }
    }

    if (mode == 0)
        final_lin<0><<<B, 128, 0, stream>>>(xs0, slices, linW, linb, (float*)d_out);
    else
        final_lin<1><<<B, 128, 0, stream>>>(xs0, slices, linW, linb, (float*)d_out);
}

// Round 3
// 3699.696 us; speedup vs baseline: 2.7177x; 2.7177x over previous
//
#include <hip/hip_runtime.h>
#include <math.h>

#define H 4
#define D 32
#define C 128
#define SC 2048

typedef unsigned short ushort_t;

// ---------- helpers ----------
__device__ __forceinline__ float bf2f(ushort_t u) {
    return __uint_as_float(((unsigned)u) << 16);
}
__device__ __forceinline__ ushort_t f2bf(float f) {
    unsigned u = __float_as_uint(f);
    u += 0x7fffu + ((u >> 16) & 1u);
    return (ushort_t)(u >> 16);
}
__device__ __forceinline__ void unpack2(unsigned w, float& a, float& b) {
    a = __uint_as_float(w << 16);
    b = __uint_as_float(w & 0xffff0000u);
}
__device__ __forceinline__ float gelu_t(float x) {
    float x3 = x * x * x;
    float t = tanhf(0.7978845608028654f * (x + 0.044715f * x3));
    return 0.5f * x * (1.0f + t);
}

// ---------- diag ----------
__global__ void diag_fill(float* out, int n, float v) {
    int i = blockIdx.x * 256 + threadIdx.x;
    if (i < n) out[i] = v;
}

// ---------- fused relation weights ----------
__global__ void fuse_weights(const float* __restrict__ kW, const float* __restrict__ kb,
                             const float* __restrict__ vW, const float* __restrict__ vb,
                             const float* __restrict__ relA, const float* __restrict__ relM,
                             float* __restrict__ fw)
{
    int bid = blockIdx.x;      // 0..11
    int le = bid >> 1;         // l*3+e
    int which = bid & 1;       // 0 = k/relA, 1 = v/relM
    int l = le / 3, e = le % 3;
    const int est[3] = {1, 0, 0};
    int st = est[e];
    const float* Wsrc = (which ? vW : kW) + (size_t)(l * 2 + st) * C * C;
    const float* bsrc = (which ? vb : kb) + (size_t)(l * 2 + st) * C;
    const float* rel  = (which ? relM : relA) + (size_t)(l * 3 + e) * H * D * D;
    float* out = fw + (size_t)(le * 2 + which) * (C * C + C);

    __shared__ float rsh[H * D * D];
    for (int i = threadIdx.x; i < H * D * D; i += 256) rsh[i] = rel[i];
    __syncthreads();

    for (int i = threadIdx.x; i < C * C; i += 256) {
        int c = i >> 7, hf = i & 127, h = hf >> 5, f = hf & 31;
        float acc = 0.f;
        #pragma unroll
        for (int d = 0; d < D; ++d)
            acc += Wsrc[c * C + h * D + d] * rsh[h * D * D + d * D + f];
        out[i] = acc;
    }
    for (int i = threadIdx.x; i < C; i += 256) {
        int h = i >> 5, f = i & 31;
        float acc = 0.f;
        #pragma unroll
        for (int d = 0; d < D; ++d)
            acc += bsrc[h * D + d] * rsh[h * D * D + d * D + f];
        out[C * C + i] = acc;
    }
}

// ---------- generic [N,128] @ [128,128] + bias, bf16 in/out, runtime row strides ----------
// PRE:  0 none, 1 gelu(x) on input
// POST: 0 none, 1 relu, 2 blend: y = g*y + (1-g)*Old
template <int INBF, int PRE, int POST>
__global__ __launch_bounds__(256) void gemm128(
    const void* __restrict__ Xv, const float* __restrict__ W,
    const float* __restrict__ bias, ushort_t* __restrict__ Yv,
    const ushort_t* __restrict__ Oldv, const float* __restrict__ skipp,
    int N, int ystride)
{
    __shared__ float Wsh[C * C];    // 64KB
    __shared__ float Xsh[64 * C];   // 32KB
    const int tid = threadIdx.x;

    {
        const float4* W4 = (const float4*)W;
        float4* Wsh4 = (float4*)Wsh;
        for (int i = tid; i < C * C / 4; i += 256) Wsh4[i] = W4[i];
    }
    const int rbase = (tid >> 5) * 8;
    const int cbase = (tid & 31) * 4;
    const float4 bb = *(const float4*)(bias + cbase);
    float g = 0.f;
    if (POST == 2) g = 1.0f / (1.0f + __expf(-skipp[0]));

    const int tiles = (N + 63) >> 6;
    for (int t = blockIdx.x; t < tiles; t += gridDim.x) {
        const int row0 = t << 6;
        __syncthreads();
        for (int i = tid; i < 64 * 32; i += 256) {
            int r = i >> 5, q4 = i & 31;
            int grow = row0 + r;
            float4 v = make_float4(0.f, 0.f, 0.f, 0.f);
            if (grow < N) {
                if (INBF) {
                    ushort4 u = *(const ushort4*)((const ushort_t*)Xv + (size_t)grow * C + q4 * 4);
                    v.x = bf2f(u.x); v.y = bf2f(u.y); v.z = bf2f(u.z); v.w = bf2f(u.w);
                } else {
                    v = ((const float4*)Xv)[(size_t)grow * 32 + q4];
                }
                if (PRE == 1) {
                    v.x = gelu_t(v.x); v.y = gelu_t(v.y);
                    v.z = gelu_t(v.z); v.w = gelu_t(v.w);
                }
            }
            *(float4*)&Xsh[r * C + q4 * 4] = v;
        }
        __syncthreads();

        float4 acc[8];
        #pragma unroll
        for (int r = 0; r < 8; ++r) acc[r] = make_float4(0.f, 0.f, 0.f, 0.f);

        for (int k = 0; k < C; k += 4) {
            float4 w0 = *(float4*)&Wsh[(k + 0) * C + cbase];
            float4 w1 = *(float4*)&Wsh[(k + 1) * C + cbase];
            float4 w2 = *(float4*)&Wsh[(k + 2) * C + cbase];
            float4 w3 = *(float4*)&Wsh[(k + 3) * C + cbase];
            #pragma unroll
            for (int r = 0; r < 8; ++r) {
                float4 xv = *(float4*)&Xsh[(rbase + r) * C + k];
                acc[r].x += xv.x * w0.x + xv.y * w1.x + xv.z * w2.x + xv.w * w3.x;
                acc[r].y += xv.x * w0.y + xv.y * w1.y + xv.z * w2.y + xv.w * w3.y;
                acc[r].z += xv.x * w0.z + xv.y * w1.z + xv.z * w2.z + xv.w * w3.z;
                acc[r].w += xv.x * w0.w + xv.y * w1.w + xv.z * w2.w + xv.w * w3.w;
            }
        }

        #pragma unroll
        for (int r = 0; r < 8; ++r) {
            int grow = row0 + rbase + r;
            if (grow < N) {
                float4 y;
                y.x = acc[r].x + bb.x; y.y = acc[r].y + bb.y;
                y.z = acc[r].z + bb.z; y.w = acc[r].w + bb.w;
                if (POST == 1) {
                    y.x = fmaxf(y.x, 0.f); y.y = fmaxf(y.y, 0.f);
                    y.z = fmaxf(y.z, 0.f); y.w = fmaxf(y.w, 0.f);
                }
                if (POST == 2) {
                    ushort4 u = *(const ushort4*)(Oldv + (size_t)grow * C + cbase);
                    float4 o = make_float4(bf2f(u.x), bf2f(u.y), bf2f(u.z), bf2f(u.w));
                    y.x = g * y.x + (1.f - g) * o.x;
                    y.y = g * y.y + (1.f - g) * o.y;
                    y.z = g * y.z + (1.f - g) * o.z;
                    y.w = g * y.w + (1.f - g) * o.w;
                }
                ushort4 s4 = make_ushort4(f2bf(y.x), f2bf(y.y), f2bf(y.z), f2bf(y.w));
                *(ushort4*)(Yv + (size_t)grow * ystride + cbase) = s4;
            }
        }
    }
}

// ---------- CSR build ----------
__global__ void hist_k(const int* __restrict__ ei, int E, int* __restrict__ cnt) {
    int i = blockIdx.x * 256 + threadIdx.x;
    if (i < E) atomicAdd(&cnt[ei[E + i]], 1);
}

__global__ __launch_bounds__(256) void scan1(const int* __restrict__ cnt, int n, int* __restrict__ part) {
    __shared__ int sh[256];
    int b = blockIdx.x, t = threadIdx.x;
    int base = b * SC + t * 8;
    int s = 0;
    #pragma unroll
    for (int j = 0; j < 8; ++j) { int i = base + j; if (i < n) s += cnt[i]; }
    sh[t] = s; __syncthreads();
    for (int off = 128; off > 0; off >>= 1) {
        if (t < off) sh[t] += sh[t + off];
        __syncthreads();
    }
    if (t == 0) part[b] = sh[0];
}

__global__ void scan2(int* part, int nb) {
    if (threadIdx.x == 0 && blockIdx.x == 0) {
        int run = 0;
        for (int i = 0; i < nb; ++i) { int v = part[i]; part[i] = run; run += v; }
        part[nb] = run;
    }
}

__global__ __launch_bounds__(256) void scan3(const int* __restrict__ cnt, int n,
                                             const int* __restrict__ part, int* __restrict__ rowptr) {
    __shared__ int sh[256];
    int b = blockIdx.x, t = threadIdx.x;
    int base = b * SC + t * 8;
    int loc[8]; int s = 0;
    #pragma unroll
    for (int j = 0; j < 8; ++j) { int i = base + j; int v = (i < n) ? cnt[i] : 0; s += v; loc[j] = s; }
    sh[t] = s; __syncthreads();
    for (int off = 1; off < 256; off <<= 1) {
        int v = (t >= off) ? sh[t - off] : 0;
        __syncthreads();
        sh[t] += v;
        __syncthreads();
    }
    int excl = (t ? sh[t - 1] : 0) + part[b];
    #pragma unroll
    for (int j = 0; j < 8; ++j) { int i = base + j; if (i < n) rowptr[i + 1] = excl + loc[j]; }
    if (b == 0 && t == 0) rowptr[0] = 0;
}

__global__ void scatter_k(const int* __restrict__ ei, int E, int* __restrict__ wp, int* __restrict__ srcs) {
    int i = blockIdx.x * 256 + threadIdx.x;
    if (i < E) {
        int pos = atomicAdd(&wp[ei[E + i]], 1);
        srcs[pos] = ei[i];
    }
}

// ---------- fused per-node attention aggregate ----------
// one wave per dst node; lane l covers channels 2l,2l+1; head = l>>4
template <int ACCUM>
__global__ __launch_bounds__(256) void edge_agg(
    const int* __restrict__ rowptr, const int* __restrict__ srcs,
    const unsigned* __restrict__ kv, const unsigned* __restrict__ qb,
    const float* __restrict__ relP, unsigned* __restrict__ agg, int Nd)
{
    int wid = (blockIdx.x * 256 + threadIdx.x) >> 6;
    int lane = threadIdx.x & 63;
    if (wid >= Nd) return;
    unsigned q2 = qb[(size_t)wid * 64 + lane];
    float q0, q1; unpack2(q2, q0, q1);
    float rp = relP[lane >> 4] * 0.17677669529663687f;  // relP[h] / sqrt(32)
    int beg = rowptr[wid], end = rowptr[wid + 1];
    float denom = 0.f, acc0 = 0.f, acc1 = 0.f;
    for (int i = beg; i < end; ++i) {
        int s = srcs[i];
        const unsigned* row = kv + (size_t)s * 128;
        unsigned k2 = row[lane], v2 = row[64 + lane];
        float k0, k1, v0, v1;
        unpack2(k2, k0, k1); unpack2(v2, v0, v1);
        float dp = k0 * q0 + k1 * q1;
        dp += __shfl_xor(dp, 1, 16);
        dp += __shfl_xor(dp, 2, 16);
        dp += __shfl_xor(dp, 4, 16);
        dp += __shfl_xor(dp, 8, 16);
        float w = __expf(dp * rp);
        denom += w;
        acc0 += w * v0; acc1 += w * v1;
    }
    float r = 1.0f / (denom + 1e-16f);
    acc0 *= r; acc1 *= r;
    if (ACCUM) {
        unsigned o = agg[(size_t)wid * 64 + lane];
        float o0, o1; unpack2(o, o0, o1);
        acc0 += o0; acc1 += o1;
    }
    agg[(size_t)wid * 64 + lane] = ((unsigned)f2bf(acc1) << 16) | (unsigned)f2bf(acc0);
}

// ---------- final: gather last visit per patient, @ linW + linb ----------
__global__ void final_lin(const ushort_t* __restrict__ xs0, const int* __restrict__ slices,
                          const float* __restrict__ Wl, const float* __restrict__ bl,
                          float* __restrict__ out)
{
    __shared__ float xr[C];
    int b = blockIdx.x, o = threadIdx.x;
    int row = slices[b + 1] - 1;
    xr[o] = bf2f(xs0[(size_t)row * C + o]);
    __syncthreads();
    float acc = bl[o];
    #pragma unroll 4
    for (int c = 0; c < C; ++c) acc += xr[c] * Wl[c * C + o];
    out[(size_t)b * C + o] = acc;
}

extern "C" void kernel_launch(void* const* d_in, const int* in_sizes, int n_in,
                              void* d_out, int out_size, void* d_ws, size_t ws_size,
                              hipStream_t stream)
{
    (void)n_in;
    const float* x_visit = (const float*)d_in[0];
    const float* x_code  = (const float*)d_in[1];
    const int* slices    = (const int*)d_in[5];
    const float* lin0_W  = (const float*)d_in[6];
    const float* lin0_b  = (const float*)d_in[7];
    const float* kW  = (const float*)d_in[8];
    const float* kb  = (const float*)d_in[9];
    const float* qW  = (const float*)d_in[10];
    const float* qb  = (const float*)d_in[11];
    const float* vW  = (const float*)d_in[12];
    const float* vb  = (const float*)d_in[13];
    const float* aW  = (const float*)d_in[14];
    const float* ab  = (const float*)d_in[15];
    const float* skip = (const float*)d_in[16];
    const float* relA = (const float*)d_in[17];
    const float* relM = (const float*)d_in[18];
    const float* relP = (const float*)d_in[19];
    const float* linW = (const float*)d_in[20];
    const float* linb = (const float*)d_in[21];

    const int NV = in_sizes[0] / C;
    const int NC = in_sizes[1] / C;
    const int NN = NV > NC ? NV : NC;
    const int B = in_sizes[5] - 1;

    const int est[3] = {1, 0, 0}, edt[3] = {0, 1, 0};
    const int* eptr[3] = {(const int*)d_in[2], (const int*)d_in[3], (const int*)d_in[4]};
    const int Ecnt[3] = {in_sizes[2] / 2, in_sizes[3] / 2, in_sizes[4] / 2};
    const int Ndrel[3] = {NV, NC, NV};

    // ---- workspace plan (all bf16 state; must stay < ~343MB proven capacity) ----
    size_t off = 0;
    auto A = [&](size_t bytes) { size_t c = off; off += (bytes + 255) & ~(size_t)255; return c; };
    size_t o_xs0  = A((size_t)NV * C * 2);
    size_t o_xs1  = A((size_t)NC * C * 2);
    size_t o_qbuf = A((size_t)(NV + NC) * C * 2);
    size_t o_kv   = A((size_t)NN * 2 * C * 2);         // interleaved k'|v' rows, 256 bf16/node
    size_t o_aggV = A((size_t)NV * C * 2);
    size_t o_aggC = A((size_t)NC * C * 2);
    size_t o_rp[3], o_srcs[3];
    for (int e = 0; e < 3; ++e) {
        o_rp[e]   = A(((size_t)Ndrel[e] + 1) * 4);
        o_srcs[e] = A((size_t)Ecnt[e] * 4);
    }
    size_t o_wp   = A(((size_t)NN + 1) * 4);
    size_t o_part = A(4096);
    size_t o_fw   = A((size_t)12 * (C * C + C) * 4);
    size_t total = off;

    if (ws_size < total) {
        float v = 10.0f + (float)((double)ws_size * 1e-9);
        diag_fill<<<(out_size + 255) / 256, 256, 0, stream>>>((float*)d_out, out_size, v);
        return;
    }

    char* base = (char*)d_ws;
    ushort_t* xs0  = (ushort_t*)(base + o_xs0);
    ushort_t* xs1  = (ushort_t*)(base + o_xs1);
    ushort_t* qbuf = (ushort_t*)(base + o_qbuf);
    ushort_t* kvb  = (ushort_t*)(base + o_kv);
    ushort_t* aggV = (ushort_t*)(base + o_aggV);
    ushort_t* aggC = (ushort_t*)(base + o_aggC);
    int* rp_[3]; int* srcs_[3];
    for (int e = 0; e < 3; ++e) { rp_[e] = (int*)(base + o_rp[e]); srcs_[e] = (int*)(base + o_srcs[e]); }
    int* wp   = (int*)(base + o_wp);
    int* part = (int*)(base + o_part);
    float* fw = (float*)(base + o_fw);

    // 1) fused relation weights
    fuse_weights<<<12, 256, 0, stream>>>(kW, kb, vW, vb, relA, relM, fw);

    auto grid_of = [](int N) { int t = (N + 63) / 64; return dim3((unsigned)(t < 1024 ? t : 1024)); };

    // 2) input projection + relu (f32 in, bf16 out)
    gemm128<0, 0, 1><<<grid_of(NV), 256, 0, stream>>>(x_visit, lin0_W, lin0_b, xs0, nullptr, nullptr, NV, C);
    gemm128<0, 0, 1><<<grid_of(NC), 256, 0, stream>>>(x_code, lin0_W + C * C, lin0_b + C, xs1, nullptr, nullptr, NC, C);

    // 3) CSR build per relation (edge lists are layer-invariant)
    for (int e = 0; e < 3; ++e) {
        int Nd = Ndrel[e], E = Ecnt[e];
        int nb = (Nd + SC - 1) / SC;
        hipMemsetAsync(wp, 0, (size_t)Nd * 4, stream);
        hist_k<<<(E + 255) / 256, 256, 0, stream>>>(eptr[e], E, wp);
        scan1<<<nb, 256, 0, stream>>>(wp, Nd, part);
        scan2<<<1, 64, 0, stream>>>(part, nb);
        scan3<<<nb, 256, 0, stream>>>(wp, Nd, part, rp_[e]);
        hipMemcpyAsync(wp, rp_[e], (size_t)Nd * 4, hipMemcpyDeviceToDevice, stream);
        scatter_k<<<(E + 255) / 256, 256, 0, stream>>>(eptr[e], E, wp, srcs_[e]);
    }

    // 4) layers
    for (int l = 0; l < 2; ++l) {
        // q projections for both node types (once per layer)
        gemm128<1, 0, 0><<<grid_of(NV), 256, 0, stream>>>(xs0, qW + (size_t)(l * 2 + 0) * C * C, qb + (l * 2 + 0) * C, qbuf, nullptr, nullptr, NV, C);
        gemm128<1, 0, 0><<<grid_of(NC), 256, 0, stream>>>(xs1, qW + (size_t)(l * 2 + 1) * C * C, qb + (l * 2 + 1) * C, qbuf + (size_t)NV * C, nullptr, nullptr, NC, C);

        for (int e = 0; e < 3; ++e) {
            const int st = est[e], dt = edt[e];
            const ushort_t* xsrc = st ? xs1 : xs0;
            const int Ns = st ? NC : NV;
            const int Nd = Ndrel[e];
            const float* fk = fw + (size_t)((l * 3 + e) * 2 + 0) * (C * C + C);
            const float* fv = fw + (size_t)((l * 3 + e) * 2 + 1) * (C * C + C);

            // k' and v' into interleaved rows (stride 256 elements)
            gemm128<1, 0, 0><<<grid_of(Ns), 256, 0, stream>>>(xsrc, fk, fk + C * C, kvb, nullptr, nullptr, Ns, 2 * C);
            gemm128<1, 0, 0><<<grid_of(Ns), 256, 0, stream>>>(xsrc, fv, fv + C * C, kvb + C, nullptr, nullptr, Ns, 2 * C);

            const unsigned* qv = (const unsigned*)(qbuf + (dt ? (size_t)NV * C : 0));
            unsigned* agg_d = (unsigned*)(dt ? aggC : aggV);
            const float* rpp = relP + (size_t)(l * 3 + e) * H;
            dim3 g((Nd + 3) / 4);
            if (e == 2)
                edge_agg<1><<<g, 256, 0, stream>>>(rp_[e], srcs_[e], (const unsigned*)kvb, qv, rpp, agg_d, Nd);
            else
                edge_agg<0><<<g, 256, 0, stream>>>(rp_[e], srcs_[e], (const unsigned*)kvb, qv, rpp, agg_d, Nd);
        }

        // node update: x = g*(gelu(agg) @ aW + ab) + (1-g)*x
        gemm128<1, 1, 2><<<grid_of(NV), 256, 0, stream>>>(aggV, aW + (size_t)(l * 2 + 0) * C * C, ab + (l * 2 + 0) * C, xs0, xs0, skip + (l * 2 + 0), NV, C);
        gemm128<1, 1, 2><<<grid_of(NC), 256, 0, stream>>>(aggC, aW + (size_t)(l * 2 + 1) * C * C, ab + (l * 2 + 1) * C, xs1, xs1, skip + (l * 2 + 1), NC, C);
    }

    // 5) last visit per patient @ linW + linb
    final_lin<<<B, 128, 0, stream>>>(xs0, slices, linW, linb, (float*)d_out);
}

// Round 4
// 1554.454 us; speedup vs baseline: 6.4684x; 2.3801x over previous
//
#include <hip/hip_runtime.h>
#include <math.h>

#define H 4
#define D 32
#define C 128
#define CC (C * C)
#define SC 2048

typedef unsigned short ushort_t;
typedef __attribute__((ext_vector_type(8))) short bf16x8;
typedef __attribute__((ext_vector_type(4))) float f32x4;

union BF8 { bf16x8 v; ushort_t u[8]; };

// ---------- helpers ----------
__device__ __forceinline__ float bf2f(ushort_t u) {
    return __uint_as_float(((unsigned)u) << 16);
}
__device__ __forceinline__ ushort_t f2bf(float f) {
    unsigned u = __float_as_uint(f);
    u += 0x7fffu + ((u >> 16) & 1u);
    return (ushort_t)(u >> 16);
}
__device__ __forceinline__ void unpack2(unsigned w, float& a, float& b) {
    a = __uint_as_float(w << 16);
    b = __uint_as_float(w & 0xffff0000u);
}
__device__ __forceinline__ float gelu_t(float x) {
    // tanh-approx gelu, tanh via exp: tanh(z) = 1 - 2/(e^2z + 1)
    float z = 0.7978845608028654f * (x + 0.044715f * x * x * x);
    float t = 1.0f - 2.0f / (__expf(2.0f * z) + 1.0f);
    return 0.5f * x * (1.0f + t);
}

// ---------- diag ----------
__global__ void diag_fill(float* out, int n, float v) {
    int i = blockIdx.x * 256 + threadIdx.x;
    if (i < n) out[i] = v;
}

// ---------- fused relation weights (fp32): W' = W @ blockdiag(rel) ----------
__global__ void fuse_weights(const float* __restrict__ kW, const float* __restrict__ kb,
                             const float* __restrict__ vW, const float* __restrict__ vb,
                             const float* __restrict__ relA, const float* __restrict__ relM,
                             float* __restrict__ fw)
{
    int bid = blockIdx.x;      // 0..11
    int le = bid >> 1;         // l*3+e
    int which = bid & 1;       // 0 = k/relA, 1 = v/relM
    int l = le / 3, e = le % 3;
    const int est[3] = {1, 0, 0};
    int st = est[e];
    const float* Wsrc = (which ? vW : kW) + (size_t)(l * 2 + st) * CC;
    const float* bsrc = (which ? vb : kb) + (size_t)(l * 2 + st) * C;
    const float* rel  = (which ? relM : relA) + (size_t)(l * 3 + e) * H * D * D;
    float* out = fw + (size_t)(le * 2 + which) * (CC + C);

    __shared__ float rsh[H * D * D];
    for (int i = threadIdx.x; i < H * D * D; i += 256) rsh[i] = rel[i];
    __syncthreads();

    for (int i = threadIdx.x; i < CC; i += 256) {
        int c = i >> 7, hf = i & 127, h = hf >> 5, f = hf & 31;
        float acc = 0.f;
        #pragma unroll
        for (int d = 0; d < D; ++d)
            acc += Wsrc[c * C + h * D + d] * rsh[h * D * D + d * D + f];
        out[i] = acc;
    }
    for (int i = threadIdx.x; i < C; i += 256) {
        int h = i >> 5, f = i & 31;
        float acc = 0.f;
        #pragma unroll
        for (int d = 0; d < D; ++d)
            acc += bsrc[h * D + d] * rsh[h * D * D + d * D + f];
        out[CC + i] = acc;
    }
}

// ---------- transpose all weights to bf16 Wt[n][k] (k contiguous) ----------
// ids: 0-1 lin0_W, 2-5 qW, 6-9 aW, 10-21 fused k/v from fw
__global__ void trans_w(const float* __restrict__ lin0_W, const float* __restrict__ qW,
                        const float* __restrict__ aW, const float* __restrict__ fw,
                        ushort_t* __restrict__ wt)
{
    int id = blockIdx.x;
    const float* src;
    if (id < 2)       src = lin0_W + (size_t)id * CC;
    else if (id < 6)  src = qW + (size_t)(id - 2) * CC;
    else if (id < 10) src = aW + (size_t)(id - 6) * CC;
    else              src = fw + (size_t)(id - 10) * (CC + C);
    ushort_t* dst = wt + (size_t)id * CC;
    for (int i = threadIdx.x; i < CC; i += 256) {
        int n = i >> 7, k = i & 127;
        dst[i] = f2bf(src[k * C + n]);
    }
}

// ---------- MFMA GEMM: [N,128] @ Wt^T + bias ----------
// INTYPE: 0 = f32 X, 1 = bf16 X
// PRE: 1 = gelu on X;  POST: 1 = relu, 2 = blend with Old
// gridDim.y = 2 selects (WtB, biasB, YB) for the dual k'/v' launch.
template <int INTYPE, int PRE, int POST>
__global__ __launch_bounds__(256) void mgemm(
    const void* __restrict__ Xv,
    const ushort_t* __restrict__ WtA, const float* __restrict__ biasA,
    const ushort_t* __restrict__ WtB, const float* __restrict__ biasB,
    ushort_t* __restrict__ YA, ushort_t* __restrict__ YB,
    const ushort_t* __restrict__ Oldv, const float* __restrict__ skipp,
    int N, int ystride)
{
    const ushort_t* Wt  = blockIdx.y ? WtB : WtA;
    const float* bias   = blockIdx.y ? biasB : biasA;
    ushort_t* Y         = blockIdx.y ? YB : YA;

    const int wave = threadIdx.x >> 6;
    const int lane = threadIdx.x & 63;
    const int lr = lane & 15;       // A-row / B-col / D-col selector
    const int lk = lane >> 4;       // k-chunk (k offset lk*8); D-row base lk*4

    float g = 0.f;
    if (POST == 2) g = 1.0f / (1.0f + __expf(-skipp[0]));
    float bcol[8];
    #pragma unroll
    for (int n = 0; n < 8; ++n) bcol[n] = bias[n * 16 + lr];

    const int tiles = (N + 127) >> 7;
    for (int t = blockIdx.x; t < tiles; t += gridDim.x) {
        const int row0 = (t << 7) + wave * 32;
        f32x4 acc[2][8];
        #pragma unroll
        for (int m = 0; m < 2; ++m)
            #pragma unroll
            for (int n = 0; n < 8; ++n)
                acc[m][n] = (f32x4){0.f, 0.f, 0.f, 0.f};

        #pragma unroll
        for (int kk = 0; kk < 4; ++kk) {
            BF8 a[2];
            #pragma unroll
            for (int m = 0; m < 2; ++m) {
                int r = row0 + m * 16 + lr;
                if (INTYPE == 0) {
                    float vv[8];
                    if (r < N) {
                        const float* p = (const float*)Xv + (size_t)r * C + kk * 32 + lk * 8;
                        float4 u0 = *(const float4*)p;
                        float4 u1 = *(const float4*)(p + 4);
                        vv[0] = u0.x; vv[1] = u0.y; vv[2] = u0.z; vv[3] = u0.w;
                        vv[4] = u1.x; vv[5] = u1.y; vv[6] = u1.z; vv[7] = u1.w;
                    } else {
                        #pragma unroll
                        for (int j = 0; j < 8; ++j) vv[j] = 0.f;
                    }
                    #pragma unroll
                    for (int j = 0; j < 8; ++j) a[m].u[j] = f2bf(PRE ? gelu_t(vv[j]) : vv[j]);
                } else {
                    if (r < N) {
                        a[m].v = *(const bf16x8*)((const ushort_t*)Xv + (size_t)r * C + kk * 32 + lk * 8);
                        if (PRE) {
                            #pragma unroll
                            for (int j = 0; j < 8; ++j) a[m].u[j] = f2bf(gelu_t(bf2f(a[m].u[j])));
                        }
                    } else {
                        #pragma unroll
                        for (int j = 0; j < 8; ++j) a[m].u[j] = 0;
                    }
                }
            }
            #pragma unroll
            for (int n = 0; n < 8; ++n) {
                BF8 b;
                b.v = *(const bf16x8*)(Wt + (size_t)(n * 16 + lr) * C + kk * 32 + lk * 8);
                #pragma unroll
                for (int m = 0; m < 2; ++m)
                    acc[m][n] = __builtin_amdgcn_mfma_f32_16x16x32_bf16(a[m].v, b.v, acc[m][n], 0, 0, 0);
            }
        }

        // epilogue: D row = lk*4 + reg (within 16), col = n*16 + lr
        #pragma unroll
        for (int m = 0; m < 2; ++m) {
            #pragma unroll
            for (int reg = 0; reg < 4; ++reg) {
                int grow = row0 + m * 16 + lk * 4 + reg;
                if (grow >= N) continue;
                ushort_t* yrow = Y + (size_t)grow * ystride;
                const ushort_t* orow = (POST == 2) ? (Oldv + (size_t)grow * C) : (const ushort_t*)0;
                #pragma unroll
                for (int n = 0; n < 8; ++n) {
                    float y = acc[m][n][reg] + bcol[n];
                    if (POST == 1) y = fmaxf(y, 0.f);
                    if (POST == 2) {
                        float o = bf2f(orow[n * 16 + lr]);
                        y = g * y + (1.f - g) * o;
                    }
                    yrow[n * 16 + lr] = f2bf(y);
                }
            }
        }
    }
}

// ---------- CSR build ----------
__global__ void hist_k(const int* __restrict__ ei, int E, int* __restrict__ cnt) {
    int i = blockIdx.x * 256 + threadIdx.x;
    if (i < E) atomicAdd(&cnt[ei[E + i]], 1);
}

__global__ __launch_bounds__(256) void scan1(const int* __restrict__ cnt, int n, int* __restrict__ part) {
    __shared__ int sh[256];
    int b = blockIdx.x, t = threadIdx.x;
    int base = b * SC + t * 8;
    int s = 0;
    #pragma unroll
    for (int j = 0; j < 8; ++j) { int i = base + j; if (i < n) s += cnt[i]; }
    sh[t] = s; __syncthreads();
    for (int off = 128; off > 0; off >>= 1) {
        if (t < off) sh[t] += sh[t + off];
        __syncthreads();
    }
    if (t == 0) part[b] = sh[0];
}

__global__ void scan2(int* part, int nb) {
    if (threadIdx.x == 0 && blockIdx.x == 0) {
        int run = 0;
        for (int i = 0; i < nb; ++i) { int v = part[i]; part[i] = run; run += v; }
        part[nb] = run;
    }
}

__global__ __launch_bounds__(256) void scan3(const int* __restrict__ cnt, int n,
                                             const int* __restrict__ part, int* __restrict__ rowptr) {
    __shared__ int sh[256];
    int b = blockIdx.x, t = threadIdx.x;
    int base = b * SC + t * 8;
    int loc[8]; int s = 0;
    #pragma unroll
    for (int j = 0; j < 8; ++j) { int i = base + j; int v = (i < n) ? cnt[i] : 0; s += v; loc[j] = s; }
    sh[t] = s; __syncthreads();
    for (int off = 1; off < 256; off <<= 1) {
        int v = (t >= off) ? sh[t - off] : 0;
        __syncthreads();
        sh[t] += v;
        __syncthreads();
    }
    int excl = (t ? sh[t - 1] : 0) + part[b];
    #pragma unroll
    for (int j = 0; j < 8; ++j) { int i = base + j; if (i < n) rowptr[i + 1] = excl + loc[j]; }
    if (b == 0 && t == 0) rowptr[0] = 0;
}

__global__ void scatter_k(const int* __restrict__ ei, int E, int* __restrict__ wp, int* __restrict__ srcs) {
    int i = blockIdx.x * 256 + threadIdx.x;
    if (i < E) {
        int pos = atomicAdd(&wp[ei[E + i]], 1);
        srcs[pos] = ei[i];
    }
}

// ---------- fused per-node attention aggregate ----------
template <int ACCUM>
__global__ __launch_bounds__(256) void edge_agg(
    const int* __restrict__ rowptr, const int* __restrict__ srcs,
    const unsigned* __restrict__ kv, const unsigned* __restrict__ qb,
    const float* __restrict__ relP, unsigned* __restrict__ agg, int Nd)
{
    int wid = (blockIdx.x * 256 + threadIdx.x) >> 6;
    int lane = threadIdx.x & 63;
    if (wid >= Nd) return;
    unsigned q2 = qb[(size_t)wid * 64 + lane];
    float q0, q1; unpack2(q2, q0, q1);
    float rp = relP[lane >> 4] * 0.17677669529663687f;
    int beg = rowptr[wid], end = rowptr[wid + 1];
    float denom = 0.f, acc0 = 0.f, acc1 = 0.f;
    for (int i = beg; i < end; ++i) {
        int s = srcs[i];
        const unsigned* row = kv + (size_t)s * 128;
        unsigned k2 = row[lane], v2 = row[64 + lane];
        float k0, k1, v0, v1;
        unpack2(k2, k0, k1); unpack2(v2, v0, v1);
        float dp = k0 * q0 + k1 * q1;
        dp += __shfl_xor(dp, 1, 16);
        dp += __shfl_xor(dp, 2, 16);
        dp += __shfl_xor(dp, 4, 16);
        dp += __shfl_xor(dp, 8, 16);
        float w = __expf(dp * rp);
        denom += w;
        acc0 += w * v0; acc1 += w * v1;
    }
    float r = 1.0f / (denom + 1e-16f);
    acc0 *= r; acc1 *= r;
    if (ACCUM) {
        unsigned o = agg[(size_t)wid * 64 + lane];
        float o0, o1; unpack2(o, o0, o1);
        acc0 += o0; acc1 += o1;
    }
    agg[(size_t)wid * 64 + lane] = ((unsigned)f2bf(acc1) << 16) | (unsigned)f2bf(acc0);
}

// ---------- final: gather last visit per patient, @ linW + linb ----------
__global__ void final_lin(const ushort_t* __restrict__ xs0, const int* __restrict__ slices,
                          const float* __restrict__ Wl, const float* __restrict__ bl,
                          float* __restrict__ out)
{
    __shared__ float xr[C];
    int b = blockIdx.x, o = threadIdx.x;
    int row = slices[b + 1] - 1;
    xr[o] = bf2f(xs0[(size_t)row * C + o]);
    __syncthreads();
    float acc = bl[o];
    #pragma unroll 4
    for (int c = 0; c < C; ++c) acc += xr[c] * Wl[c * C + o];
    out[(size_t)b * C + o] = acc;
}

extern "C" void kernel_launch(void* const* d_in, const int* in_sizes, int n_in,
                              void* d_out, int out_size, void* d_ws, size_t ws_size,
                              hipStream_t stream)
{
    (void)n_in;
    const float* x_visit = (const float*)d_in[0];
    const float* x_code  = (const float*)d_in[1];
    const int* slices    = (const int*)d_in[5];
    const float* lin0_W  = (const float*)d_in[6];
    const float* lin0_b  = (const float*)d_in[7];
    const float* kW  = (const float*)d_in[8];
    const float* kb  = (const float*)d_in[9];
    const float* qW  = (const float*)d_in[10];
    const float* qb  = (const float*)d_in[11];
    const float* vW  = (const float*)d_in[12];
    const float* vb  = (const float*)d_in[13];
    const float* aW  = (const float*)d_in[14];
    const float* ab  = (const float*)d_in[15];
    const float* skip = (const float*)d_in[16];
    const float* relA = (const float*)d_in[17];
    const float* relM = (const float*)d_in[18];
    const float* relP = (const float*)d_in[19];
    const float* linW = (const float*)d_in[20];
    const float* linb = (const float*)d_in[21];

    const int NV = in_sizes[0] / C;
    const int NC = in_sizes[1] / C;
    const int NN = NV > NC ? NV : NC;
    const int B = in_sizes[5] - 1;

    const int est[3] = {1, 0, 0}, edt[3] = {0, 1, 0};
    const int* eptr[3] = {(const int*)d_in[2], (const int*)d_in[3], (const int*)d_in[4]};
    const int Ecnt[3] = {in_sizes[2] / 2, in_sizes[3] / 2, in_sizes[4] / 2};
    const int Ndrel[3] = {NV, NC, NV};

    // ---- workspace plan ----
    size_t off = 0;
    auto A = [&](size_t bytes) { size_t c = off; off += (bytes + 255) & ~(size_t)255; return c; };
    size_t o_xs0  = A((size_t)NV * C * 2);
    size_t o_xs1  = A((size_t)NC * C * 2);
    size_t o_qbuf = A((size_t)(NV + NC) * C * 2);
    size_t o_kv   = A((size_t)NN * 2 * C * 2);
    size_t o_aggV = A((size_t)NV * C * 2);
    size_t o_aggC = A((size_t)NC * C * 2);
    size_t o_rp[3], o_srcs[3];
    for (int e = 0; e < 3; ++e) {
        o_rp[e]   = A(((size_t)Ndrel[e] + 1) * 4);
        o_srcs[e] = A((size_t)Ecnt[e] * 4);
    }
    size_t o_wp   = A(((size_t)NN + 1) * 4);
    size_t o_part = A(4096);
    size_t o_fw   = A((size_t)12 * (CC + C) * 4);
    size_t o_wt   = A((size_t)22 * CC * 2);
    size_t total = off;

    if (ws_size < total) {
        float v = 10.0f + (float)((double)ws_size * 1e-9);
        diag_fill<<<(out_size + 255) / 256, 256, 0, stream>>>((float*)d_out, out_size, v);
        return;
    }

    char* base = (char*)d_ws;
    ushort_t* xs0  = (ushort_t*)(base + o_xs0);
    ushort_t* xs1  = (ushort_t*)(base + o_xs1);
    ushort_t* qbuf = (ushort_t*)(base + o_qbuf);
    ushort_t* kvb  = (ushort_t*)(base + o_kv);
    ushort_t* aggV = (ushort_t*)(base + o_aggV);
    ushort_t* aggC = (ushort_t*)(base + o_aggC);
    int* rp_[3]; int* srcs_[3];
    for (int e = 0; e < 3; ++e) { rp_[e] = (int*)(base + o_rp[e]); srcs_[e] = (int*)(base + o_srcs[e]); }
    int* wp   = (int*)(base + o_wp);
    int* part = (int*)(base + o_part);
    float* fw = (float*)(base + o_fw);
    ushort_t* wt = (ushort_t*)(base + o_wt);

    // weight id helpers
    auto wt_q = [&](int l, int t) { return wt + (size_t)(2 + l * 2 + t) * CC; };
    auto wt_a = [&](int l, int t) { return wt + (size_t)(6 + l * 2 + t) * CC; };
    auto wt_f = [&](int le, int which) { return wt + (size_t)(10 + le * 2 + which) * CC; };

    // 1) fused relation weights (fp32) then transpose everything to bf16 Wt
    fuse_weights<<<12, 256, 0, stream>>>(kW, kb, vW, vb, relA, relM, fw);
    trans_w<<<22, 256, 0, stream>>>(lin0_W, qW, aW, fw, wt);

    auto grid_of = [](int N) { int t = (N + 127) / 128; return (unsigned)(t < 8192 ? t : 8192); };

    // 2) input projection + relu (f32 in, bf16 out)
    mgemm<0, 0, 1><<<dim3(grid_of(NV), 1), 256, 0, stream>>>(
        x_visit, wt + 0 * CC, lin0_b, wt, lin0_b, xs0, xs0, nullptr, nullptr, NV, C);
    mgemm<0, 0, 1><<<dim3(grid_of(NC), 1), 256, 0, stream>>>(
        x_code, wt + 1 * CC, lin0_b + C, wt, lin0_b, xs1, xs1, nullptr, nullptr, NC, C);

    // 3) CSR build per relation
    for (int e = 0; e < 3; ++e) {
        int Nd = Ndrel[e], E = Ecnt[e];
        int nb = (Nd + SC - 1) / SC;
        hipMemsetAsync(wp, 0, (size_t)Nd * 4, stream);
        hist_k<<<(E + 255) / 256, 256, 0, stream>>>(eptr[e], E, wp);
        scan1<<<nb, 256, 0, stream>>>(wp, Nd, part);
        scan2<<<1, 64, 0, stream>>>(part, nb);
        scan3<<<nb, 256, 0, stream>>>(wp, Nd, part, rp_[e]);
        hipMemcpyAsync(wp, rp_[e], (size_t)Nd * 4, hipMemcpyDeviceToDevice, stream);
        scatter_k<<<(E + 255) / 256, 256, 0, stream>>>(eptr[e], E, wp, srcs_[e]);
    }

    // 4) layers
    for (int l = 0; l < 2; ++l) {
        // q projections
        mgemm<1, 0, 0><<<dim3(grid_of(NV), 1), 256, 0, stream>>>(
            xs0, wt_q(l, 0), qb + (l * 2 + 0) * C, wt, qb, qbuf, qbuf, nullptr, nullptr, NV, C);
        mgemm<1, 0, 0><<<dim3(grid_of(NC), 1), 256, 0, stream>>>(
            xs1, wt_q(l, 1), qb + (l * 2 + 1) * C, wt, qb, qbuf + (size_t)NV * C, qbuf + (size_t)NV * C, nullptr, nullptr, NC, C);

        for (int e = 0; e < 3; ++e) {
            const int st = est[e], dt = edt[e];
            const ushort_t* xsrc = st ? xs1 : xs0;
            const int Ns = st ? NC : NV;
            const int Nd = Ndrel[e];
            const int le = l * 3 + e;
            const float* fkb = fw + (size_t)(le * 2 + 0) * (CC + C) + CC;
            const float* fvb = fw + (size_t)(le * 2 + 1) * (CC + C) + CC;

            // dual launch: y=0 -> k' (out kvb), y=1 -> v' (out kvb+C); stride 256
            mgemm<1, 0, 0><<<dim3(grid_of(Ns), 2), 256, 0, stream>>>(
                xsrc, wt_f(le, 0), fkb, wt_f(le, 1), fvb, kvb, kvb + C, nullptr, nullptr, Ns, 2 * C);

            const unsigned* qv = (const unsigned*)(qbuf + (dt ? (size_t)NV * C : 0));
            unsigned* agg_d = (unsigned*)(dt ? aggC : aggV);
            const float* rpp = relP + (size_t)le * H;
            dim3 g((Nd + 3) / 4);
            if (e == 2)
                edge_agg<1><<<g, 256, 0, stream>>>(rp_[e], srcs_[e], (const unsigned*)kvb, qv, rpp, agg_d, Nd);
            else
                edge_agg<0><<<g, 256, 0, stream>>>(rp_[e], srcs_[e], (const unsigned*)kvb, qv, rpp, agg_d, Nd);
        }

        // node update: x = g*(gelu(agg) @ aW + ab) + (1-g)*x
        mgemm<1, 1, 2><<<dim3(grid_of(NV), 1), 256, 0, stream>>>(
            aggV, wt_a(l, 0), ab + (l * 2 + 0) * C, wt, ab, xs0, xs0, xs0, skip + (l * 2 + 0), NV, C);
        mgemm<1, 1, 2><<<dim3(grid_of(NC), 1), 256, 0, stream>>>(
            aggC, wt_a(l, 1), ab + (l * 2 + 1) * C, wt, ab, xs1, xs1, xs1, skip + (l * 2 + 1), NC, C);
    }

    // 5) last visit per patient @ linW + linb
    final_lin<<<B, 128, 0, stream>>>(xs0, slices, linW, linb, (float*)d_out);
}

// Round 5
// 1430.627 us; speedup vs baseline: 7.0283x; 1.0866x over previous
//
#include <hip/hip_runtime.h>
#include <math.h>

#define H 4
#define D 32
#define C 128
#define CC (C * C)
#define SC 2048

typedef unsigned short ushort_t;
typedef __attribute__((ext_vector_type(8))) short bf16x8;
typedef __attribute__((ext_vector_type(4))) float f32x4;

union BF8 { bf16x8 v; ushort_t u[8]; };

// ---------- helpers ----------
__device__ __forceinline__ float bf2f(ushort_t u) {
    return __uint_as_float(((unsigned)u) << 16);
}
__device__ __forceinline__ ushort_t f2bf(float f) {
    unsigned u = __float_as_uint(f);
    u += 0x7fffu + ((u >> 16) & 1u);
    return (ushort_t)(u >> 16);
}
__device__ __forceinline__ void unpack2(unsigned w, float& a, float& b) {
    a = __uint_as_float(w << 16);
    b = __uint_as_float(w & 0xffff0000u);
}
__device__ __forceinline__ float gelu_t(float x) {
    float z = 0.7978845608028654f * (x + 0.044715f * x * x * x);
    float t = 1.0f - 2.0f / (__expf(2.0f * z) + 1.0f);
    return 0.5f * x * (1.0f + t);
}

// ---------- diag ----------
__global__ void diag_fill(float* out, int n, float v) {
    int i = blockIdx.x * 256 + threadIdx.x;
    if (i < n) out[i] = v;
}

// ---------- fused relation weights (fp32): W' = W @ blockdiag(rel) ----------
__global__ void fuse_weights(const float* __restrict__ kW, const float* __restrict__ kb,
                             const float* __restrict__ vW, const float* __restrict__ vb,
                             const float* __restrict__ relA, const float* __restrict__ relM,
                             float* __restrict__ fw)
{
    int bid = blockIdx.x;      // 0..11
    int le = bid >> 1;         // l*3+e
    int which = bid & 1;       // 0 = k/relA, 1 = v/relM
    int l = le / 3, e = le % 3;
    const int est[3] = {1, 0, 0};
    int st = est[e];
    const float* Wsrc = (which ? vW : kW) + (size_t)(l * 2 + st) * CC;
    const float* bsrc = (which ? vb : kb) + (size_t)(l * 2 + st) * C;
    const float* rel  = (which ? relM : relA) + (size_t)(l * 3 + e) * H * D * D;
    float* out = fw + (size_t)(le * 2 + which) * (CC + C);

    __shared__ float rsh[H * D * D];
    for (int i = threadIdx.x; i < H * D * D; i += 256) rsh[i] = rel[i];
    __syncthreads();

    for (int i = threadIdx.x; i < CC; i += 256) {
        int c = i >> 7, hf = i & 127, h = hf >> 5, f = hf & 31;
        float acc = 0.f;
        #pragma unroll
        for (int d = 0; d < D; ++d)
            acc += Wsrc[c * C + h * D + d] * rsh[h * D * D + d * D + f];
        out[i] = acc;
    }
    for (int i = threadIdx.x; i < C; i += 256) {
        int h = i >> 5, f = i & 31;
        float acc = 0.f;
        #pragma unroll
        for (int d = 0; d < D; ++d)
            acc += bsrc[h * D + d] * rsh[h * D * D + d * D + f];
        out[CC + i] = acc;
    }
}

// ---------- transpose all weights to bf16 Wt[n][k] (k contiguous) ----------
// ids: 0-1 lin0_W, 2-5 qW, 6-9 aW, 10-21 fused k/v from fw
__global__ void trans_w(const float* __restrict__ lin0_W, const float* __restrict__ qW,
                        const float* __restrict__ aW, const float* __restrict__ fw,
                        ushort_t* __restrict__ wt)
{
    int id = blockIdx.x;
    const float* src;
    if (id < 2)       src = lin0_W + (size_t)id * CC;
    else if (id < 6)  src = qW + (size_t)(id - 2) * CC;
    else if (id < 10) src = aW + (size_t)(id - 6) * CC;
    else              src = fw + (size_t)(id - 10) * (CC + C);
    ushort_t* dst = wt + (size_t)id * CC;
    for (int i = threadIdx.x; i < CC; i += 256) {
        int n = i >> 7, k = i & 127;
        dst[i] = f2bf(src[k * C + n]);
    }
}

// ---------- multi-weight MFMA GEMM: Y_w = [N,128]@Wt_w^T + b_w for w<NW ----------
struct WJob { const ushort_t* w; const float* b; ushort_t* y; int ystride; };
template <int NW> struct WArr { WJob j[NW]; };

// INTYPE: 0 = f32 X, 1 = bf16 X.  PRE: 1 = gelu on X.  POST: 1 = relu, 2 = blend with Old
template <int NW, int INTYPE, int PRE, int POST>
__global__ __launch_bounds__(256, 4) void mgemmN(
    const void* __restrict__ Xv, WArr<NW> W,
    const ushort_t* __restrict__ Oldv, const float* __restrict__ skipp, int N)
{
    const int wave = threadIdx.x >> 6, lane = threadIdx.x & 63;
    const int wr = wave >> 1, wc = wave & 1;
    const int lr = lane & 15, lk = lane >> 4;

    float g = 0.f;
    if (POST == 2) g = 1.0f / (1.0f + __expf(-skipp[0]));

    const int tiles = (N + 63) >> 6;
    for (int t = blockIdx.x; t < tiles; t += gridDim.x) {
        const int rbase = (t << 6) + wr * 32;
        // hold full-K A fragments in registers (reused across all NW weights)
        BF8 a[2][4];
        #pragma unroll
        for (int m = 0; m < 2; ++m) {
            const int r = rbase + m * 16 + lr;
            if (INTYPE == 0) {
                #pragma unroll
                for (int kk = 0; kk < 4; ++kk) {
                    float vv[8];
                    if (r < N) {
                        const float* p = (const float*)Xv + (size_t)r * C + kk * 32 + lk * 8;
                        float4 u0 = *(const float4*)p;
                        float4 u1 = *(const float4*)(p + 4);
                        vv[0] = u0.x; vv[1] = u0.y; vv[2] = u0.z; vv[3] = u0.w;
                        vv[4] = u1.x; vv[5] = u1.y; vv[6] = u1.z; vv[7] = u1.w;
                    } else {
                        #pragma unroll
                        for (int jj = 0; jj < 8; ++jj) vv[jj] = 0.f;
                    }
                    #pragma unroll
                    for (int jj = 0; jj < 8; ++jj) a[m][kk].u[jj] = f2bf(PRE ? gelu_t(vv[jj]) : vv[jj]);
                }
            } else {
                #pragma unroll
                for (int kk = 0; kk < 4; ++kk) {
                    if (r < N) {
                        a[m][kk].v = *(const bf16x8*)((const ushort_t*)Xv + (size_t)r * C + kk * 32 + lk * 8);
                        if (PRE) {
                            #pragma unroll
                            for (int jj = 0; jj < 8; ++jj) a[m][kk].u[jj] = f2bf(gelu_t(bf2f(a[m][kk].u[jj])));
                        }
                    } else {
                        #pragma unroll
                        for (int jj = 0; jj < 8; ++jj) a[m][kk].u[jj] = 0;
                    }
                }
            }
        }

        #pragma unroll
        for (int w = 0; w < NW; ++w) {
            const ushort_t* Wt = W.j[w].w;
            f32x4 acc[2][4];
            #pragma unroll
            for (int m = 0; m < 2; ++m)
                #pragma unroll
                for (int n = 0; n < 4; ++n)
                    acc[m][n] = (f32x4){0.f, 0.f, 0.f, 0.f};

            #pragma unroll
            for (int kk = 0; kk < 4; ++kk) {
                #pragma unroll
                for (int n = 0; n < 4; ++n) {
                    BF8 b;
                    b.v = *(const bf16x8*)(Wt + (size_t)(wc * 64 + n * 16 + lr) * C + kk * 32 + lk * 8);
                    acc[0][n] = __builtin_amdgcn_mfma_f32_16x16x32_bf16(a[0][kk].v, b.v, acc[0][n], 0, 0, 0);
                    acc[1][n] = __builtin_amdgcn_mfma_f32_16x16x32_bf16(a[1][kk].v, b.v, acc[1][n], 0, 0, 0);
                }
            }

            const float* bias = W.j[w].b;
            ushort_t* Y = W.j[w].y;
            const int ystride = W.j[w].ystride;
            float bcol[4];
            #pragma unroll
            for (int n = 0; n < 4; ++n) bcol[n] = bias[wc * 64 + n * 16 + lr];

            #pragma unroll
            for (int m = 0; m < 2; ++m) {
                #pragma unroll
                for (int reg = 0; reg < 4; ++reg) {
                    const int grow = rbase + m * 16 + lk * 4 + reg;
                    if (grow >= N) continue;
                    ushort_t* yrow = Y + (size_t)grow * ystride;
                    const ushort_t* orow = (POST == 2) ? (Oldv + (size_t)grow * C) : (const ushort_t*)0;
                    #pragma unroll
                    for (int n = 0; n < 4; ++n) {
                        float y = acc[m][n][reg] + bcol[n];
                        if (POST == 1) y = fmaxf(y, 0.f);
                        if (POST == 2) {
                            float o = bf2f(orow[wc * 64 + n * 16 + lr]);
                            y = g * y + (1.f - g) * o;
                        }
                        yrow[wc * 64 + n * 16 + lr] = f2bf(y);
                    }
                }
            }
        }
    }
}

// ---------- CSR build ----------
__global__ void hist_k(const int* __restrict__ ei, int E, int* __restrict__ cnt) {
    int i = blockIdx.x * 256 + threadIdx.x;
    if (i < E) atomicAdd(&cnt[ei[E + i]], 1);
}

__global__ __launch_bounds__(256) void scan1(const int* __restrict__ cnt, int n, int* __restrict__ part) {
    __shared__ int sh[256];
    int b = blockIdx.x, t = threadIdx.x;
    int base = b * SC + t * 8;
    int s = 0;
    #pragma unroll
    for (int j = 0; j < 8; ++j) { int i = base + j; if (i < n) s += cnt[i]; }
    sh[t] = s; __syncthreads();
    for (int off = 128; off > 0; off >>= 1) {
        if (t < off) sh[t] += sh[t + off];
        __syncthreads();
    }
    if (t == 0) part[b] = sh[0];
}

__global__ void scan2(int* part, int nb) {
    if (threadIdx.x == 0 && blockIdx.x == 0) {
        int run = 0;
        for (int i = 0; i < nb; ++i) { int v = part[i]; part[i] = run; run += v; }
        part[nb] = run;
    }
}

__global__ __launch_bounds__(256) void scan3(const int* __restrict__ cnt, int n,
                                             const int* __restrict__ part, int* __restrict__ rowptr) {
    __shared__ int sh[256];
    int b = blockIdx.x, t = threadIdx.x;
    int base = b * SC + t * 8;
    int loc[8]; int s = 0;
    #pragma unroll
    for (int j = 0; j < 8; ++j) { int i = base + j; int v = (i < n) ? cnt[i] : 0; s += v; loc[j] = s; }
    sh[t] = s; __syncthreads();
    for (int off = 1; off < 256; off <<= 1) {
        int v = (t >= off) ? sh[t - off] : 0;
        __syncthreads();
        sh[t] += v;
        __syncthreads();
    }
    int excl = (t ? sh[t - 1] : 0) + part[b];
    #pragma unroll
    for (int j = 0; j < 8; ++j) { int i = base + j; if (i < n) rowptr[i + 1] = excl + loc[j]; }
    if (b == 0 && t == 0) rowptr[0] = 0;
}

__global__ void scatter_k(const int* __restrict__ ei, int E, int* __restrict__ wp, int* __restrict__ srcs) {
    int i = blockIdx.x * 256 + threadIdx.x;
    if (i < E) {
        int pos = atomicAdd(&wp[ei[E + i]], 1);
        srcs[pos] = ei[i];
    }
}

// ---------- per-node attention aggregate, single relation ----------
template <int ACCUM>
__global__ __launch_bounds__(256) void edge_agg1(
    const int* __restrict__ rowptr, const int* __restrict__ srcs,
    const unsigned* __restrict__ kv, const unsigned* __restrict__ qv,
    const float* __restrict__ relP, unsigned* __restrict__ agg, int Nd)
{
    int wid = (blockIdx.x * 256 + threadIdx.x) >> 6;
    int lane = threadIdx.x & 63;
    if (wid >= Nd) return;
    unsigned q2 = qv[(size_t)wid * 64 + lane];
    float q0, q1; unpack2(q2, q0, q1);
    float rp = relP[lane >> 4] * 0.17677669529663687f;
    int beg = rowptr[wid], end = rowptr[wid + 1];
    float denom = 0.f, acc0 = 0.f, acc1 = 0.f;
    for (int i = beg; i < end; ++i) {
        int s = srcs[i];
        const unsigned* row = kv + (size_t)s * 128;
        unsigned k2 = row[lane], v2 = row[64 + lane];
        float k0, k1, v0, v1;
        unpack2(k2, k0, k1); unpack2(v2, v0, v1);
        float dp = k0 * q0 + k1 * q1;
        dp += __shfl_xor(dp, 1, 16);
        dp += __shfl_xor(dp, 2, 16);
        dp += __shfl_xor(dp, 4, 16);
        dp += __shfl_xor(dp, 8, 16);
        float w = __expf(dp * rp);
        denom += w;
        acc0 += w * v0; acc1 += w * v1;
    }
    float r = 1.0f / (denom + 1e-16f);
    acc0 *= r; acc1 *= r;
    if (ACCUM) {
        unsigned o = agg[(size_t)wid * 64 + lane];
        float o0, o1; unpack2(o, o0, o1);
        acc0 += o0; acc1 += o1;
    }
    agg[(size_t)wid * 64 + lane] = ((unsigned)f2bf(acc1) << 16) | (unsigned)f2bf(acc0);
}

// ---------- merged: two relations into one dst set (visits: e=0 and e=2) ----------
__global__ __launch_bounds__(256) void edge_agg2(
    const int* __restrict__ rp0, const int* __restrict__ s0, const unsigned* __restrict__ kv0,
    const int* __restrict__ rp2, const int* __restrict__ s2, const unsigned* __restrict__ kv2,
    const unsigned* __restrict__ qv, const float* __restrict__ relP0, const float* __restrict__ relP2,
    unsigned* __restrict__ agg, int Nd)
{
    int wid = (blockIdx.x * 256 + threadIdx.x) >> 6;
    int lane = threadIdx.x & 63;
    if (wid >= Nd) return;
    unsigned q2 = qv[(size_t)wid * 64 + lane];
    float q0, q1; unpack2(q2, q0, q1);
    float rpA = relP0[lane >> 4] * 0.17677669529663687f;
    float rpB = relP2[lane >> 4] * 0.17677669529663687f;
    float out0 = 0.f, out1 = 0.f;
    {
        int beg = rp0[wid], end = rp0[wid + 1];
        float denom = 0.f, a0 = 0.f, a1 = 0.f;
        for (int i = beg; i < end; ++i) {
            const unsigned* row = kv0 + (size_t)s0[i] * 128;
            unsigned k2 = row[lane], v2 = row[64 + lane];
            float k0, k1, v0, v1;
            unpack2(k2, k0, k1); unpack2(v2, v0, v1);
            float dp = k0 * q0 + k1 * q1;
            dp += __shfl_xor(dp, 1, 16);
            dp += __shfl_xor(dp, 2, 16);
            dp += __shfl_xor(dp, 4, 16);
            dp += __shfl_xor(dp, 8, 16);
            float w = __expf(dp * rpA);
            denom += w; a0 += w * v0; a1 += w * v1;
        }
        float r = 1.0f / (denom + 1e-16f);
        out0 += a0 * r; out1 += a1 * r;
    }
    {
        int beg = rp2[wid], end = rp2[wid + 1];
        float denom = 0.f, a0 = 0.f, a1 = 0.f;
        for (int i = beg; i < end; ++i) {
            const unsigned* row = kv2 + (size_t)s2[i] * 128;
            unsigned k2 = row[lane], v2 = row[64 + lane];
            float k0, k1, v0, v1;
            unpack2(k2, k0, k1); unpack2(v2, v0, v1);
            float dp = k0 * q0 + k1 * q1;
            dp += __shfl_xor(dp, 1, 16);
            dp += __shfl_xor(dp, 2, 16);
            dp += __shfl_xor(dp, 4, 16);
            dp += __shfl_xor(dp, 8, 16);
            float w = __expf(dp * rpB);
            denom += w; a0 += w * v0; a1 += w * v1;
        }
        float r = 1.0f / (denom + 1e-16f);
        out0 += a0 * r; out1 += a1 * r;
    }
    agg[(size_t)wid * 64 + lane] = ((unsigned)f2bf(out1) << 16) | (unsigned)f2bf(out0);
}

// ---------- final: gather last visit per patient, @ linW + linb ----------
__global__ void final_lin(const ushort_t* __restrict__ xs0, const int* __restrict__ slices,
                          const float* __restrict__ Wl, const float* __restrict__ bl,
                          float* __restrict__ out)
{
    __shared__ float xr[C];
    int b = blockIdx.x, o = threadIdx.x;
    int row = slices[b + 1] - 1;
    xr[o] = bf2f(xs0[(size_t)row * C + o]);
    __syncthreads();
    float acc = bl[o];
    #pragma unroll 4
    for (int c = 0; c < C; ++c) acc += xr[c] * Wl[c * C + o];
    out[(size_t)b * C + o] = acc;
}

extern "C" void kernel_launch(void* const* d_in, const int* in_sizes, int n_in,
                              void* d_out, int out_size, void* d_ws, size_t ws_size,
                              hipStream_t stream)
{
    (void)n_in;
    const float* x_visit = (const float*)d_in[0];
    const float* x_code  = (const float*)d_in[1];
    const int* slices    = (const int*)d_in[5];
    const float* lin0_W  = (const float*)d_in[6];
    const float* lin0_b  = (const float*)d_in[7];
    const float* kW  = (const float*)d_in[8];
    const float* kb  = (const float*)d_in[9];
    const float* qW  = (const float*)d_in[10];
    const float* qb  = (const float*)d_in[11];
    const float* vW  = (const float*)d_in[12];
    const float* vb  = (const float*)d_in[13];
    const float* aW  = (const float*)d_in[14];
    const float* ab  = (const float*)d_in[15];
    const float* skip = (const float*)d_in[16];
    const float* relA = (const float*)d_in[17];
    const float* relM = (const float*)d_in[18];
    const float* relP = (const float*)d_in[19];
    const float* linW = (const float*)d_in[20];
    const float* linb = (const float*)d_in[21];

    const int NV = in_sizes[0] / C;
    const int NC = in_sizes[1] / C;
    const int NN = NV > NC ? NV : NC;
    const int B = in_sizes[5] - 1;

    const int est[3] = {1, 0, 0}, edt[3] = {0, 1, 0};
    const int* eptr[3] = {(const int*)d_in[2], (const int*)d_in[3], (const int*)d_in[4]};
    const int Ecnt[3] = {in_sizes[2] / 2, in_sizes[3] / 2, in_sizes[4] / 2};
    const int Ndrel[3] = {NV, NC, NV};
    const int Nsrel[3] = {NC, NV, NV};

    // ---- workspace plan: common block, then plan-A (per-relation kv) or plan-B (shared kv) ----
    size_t off = 0;
    auto AL = [&](size_t bytes) { size_t c = off; off += (bytes + 255) & ~(size_t)255; return c; };
    size_t o_xs0  = AL((size_t)NV * C * 2);
    size_t o_xs1  = AL((size_t)NC * C * 2);
    size_t o_q0   = AL((size_t)NV * C * 2);
    size_t o_q1   = AL((size_t)NC * C * 2);
    size_t o_aggV = AL((size_t)NV * C * 2);
    size_t o_aggC = AL((size_t)NC * C * 2);
    size_t o_rp[3], o_srcs[3];
    for (int e = 0; e < 3; ++e) {
        o_rp[e]   = AL(((size_t)Ndrel[e] + 1) * 4);
        o_srcs[e] = AL((size_t)Ecnt[e] * 4);
    }
    size_t o_wp   = AL(((size_t)NN + 1) * 4);
    size_t o_part = AL(4096);
    size_t o_fw   = AL((size_t)12 * (CC + C) * 4);
    size_t o_wt   = AL((size_t)22 * CC * 2);
    size_t common_end = off;

    // plan A: kv per relation
    size_t o_kvA[3];
    for (int e = 0; e < 3; ++e) o_kvA[e] = AL((size_t)Nsrel[e] * 2 * C * 2);
    size_t totalA = off;
    // plan B: one shared kv
    off = common_end;
    size_t o_kvB = AL((size_t)NN * 2 * C * 2);
    size_t totalB = off;

    int planA;
    if (ws_size >= totalA) planA = 1;
    else if (ws_size >= totalB) planA = 0;
    else {
        float v = 10.0f + (float)((double)ws_size * 1e-9);
        diag_fill<<<(out_size + 255) / 256, 256, 0, stream>>>((float*)d_out, out_size, v);
        return;
    }

    char* base = (char*)d_ws;
    ushort_t* xs0  = (ushort_t*)(base + o_xs0);
    ushort_t* xs1  = (ushort_t*)(base + o_xs1);
    ushort_t* q0   = (ushort_t*)(base + o_q0);
    ushort_t* q1   = (ushort_t*)(base + o_q1);
    ushort_t* aggV = (ushort_t*)(base + o_aggV);
    ushort_t* aggC = (ushort_t*)(base + o_aggC);
    int* rp_[3]; int* srcs_[3];
    for (int e = 0; e < 3; ++e) { rp_[e] = (int*)(base + o_rp[e]); srcs_[e] = (int*)(base + o_srcs[e]); }
    int* wp   = (int*)(base + o_wp);
    int* part = (int*)(base + o_part);
    float* fw = (float*)(base + o_fw);
    ushort_t* wt = (ushort_t*)(base + o_wt);
    ushort_t* kvA[3];
    for (int e = 0; e < 3; ++e) kvA[e] = (ushort_t*)(base + (planA ? o_kvA[e] : o_kvB));
    ushort_t* kvB = (ushort_t*)(base + o_kvB);

    auto wt_q = [&](int l, int t) { return wt + (size_t)(2 + l * 2 + t) * CC; };
    auto wt_a = [&](int l, int t) { return wt + (size_t)(6 + l * 2 + t) * CC; };
    auto wt_f = [&](int le, int which) { return wt + (size_t)(10 + le * 2 + which) * CC; };
    auto fb   = [&](int le, int which) { return fw + (size_t)(le * 2 + which) * (CC + C) + CC; };

    // 1) fused relation weights + bf16 transposed weights
    fuse_weights<<<12, 256, 0, stream>>>(kW, kb, vW, vb, relA, relM, fw);
    trans_w<<<22, 256, 0, stream>>>(lin0_W, qW, aW, fw, wt);

    auto grid_of = [](int N) { unsigned t = (unsigned)((N + 63) / 64); return t < 32768u ? t : 32768u; };

    // 2) input projection + relu (f32 in, bf16 out)
    {
        WArr<1> j; j.j[0] = {wt + 0 * CC, lin0_b, xs0, C};
        mgemmN<1, 0, 0, 1><<<grid_of(NV), 256, 0, stream>>>(x_visit, j, nullptr, nullptr, NV);
        WArr<1> k; k.j[0] = {wt + 1 * CC, lin0_b + C, xs1, C};
        mgemmN<1, 0, 0, 1><<<grid_of(NC), 256, 0, stream>>>(x_code, k, nullptr, nullptr, NC);
    }

    // 3) CSR build per relation
    for (int e = 0; e < 3; ++e) {
        int Nd = Ndrel[e], E = Ecnt[e];
        int nb = (Nd + SC - 1) / SC;
        hipMemsetAsync(wp, 0, (size_t)Nd * 4, stream);
        hist_k<<<(E + 255) / 256, 256, 0, stream>>>(eptr[e], E, wp);
        scan1<<<nb, 256, 0, stream>>>(wp, Nd, part);
        scan2<<<1, 64, 0, stream>>>(part, nb);
        scan3<<<nb, 256, 0, stream>>>(wp, Nd, part, rp_[e]);
        hipMemcpyAsync(wp, rp_[e], (size_t)Nd * 4, hipMemcpyDeviceToDevice, stream);
        scatter_k<<<(E + 255) / 256, 256, 0, stream>>>(eptr[e], E, wp, srcs_[e]);
    }

    // 4) layers
    for (int l = 0; l < 2; ++l) {
        if (planA) {
            // fused: xs0 -> {q0, kv1(k,v), kv2(k,v)}
            {
                WArr<5> j;
                j.j[0] = {wt_q(l, 0), qb + (l * 2 + 0) * C, q0, C};
                j.j[1] = {wt_f(l * 3 + 1, 0), fb(l * 3 + 1, 0), kvA[1], 2 * C};
                j.j[2] = {wt_f(l * 3 + 1, 1), fb(l * 3 + 1, 1), kvA[1] + C, 2 * C};
                j.j[3] = {wt_f(l * 3 + 2, 0), fb(l * 3 + 2, 0), kvA[2], 2 * C};
                j.j[4] = {wt_f(l * 3 + 2, 1), fb(l * 3 + 2, 1), kvA[2] + C, 2 * C};
                mgemmN<5, 1, 0, 0><<<grid_of(NV), 256, 0, stream>>>(xs0, j, nullptr, nullptr, NV);
            }
            // fused: xs1 -> {q1, kv0(k,v)}
            {
                WArr<3> j;
                j.j[0] = {wt_q(l, 1), qb + (l * 2 + 1) * C, q1, C};
                j.j[1] = {wt_f(l * 3 + 0, 0), fb(l * 3 + 0, 0), kvA[0], 2 * C};
                j.j[2] = {wt_f(l * 3 + 0, 1), fb(l * 3 + 0, 1), kvA[0] + C, 2 * C};
                mgemmN<3, 1, 0, 0><<<grid_of(NC), 256, 0, stream>>>(xs1, j, nullptr, nullptr, NC);
            }
            // visits: relations 0 and 2 merged; codes: relation 1
            edge_agg2<<<(NV + 3) / 4, 256, 0, stream>>>(
                rp_[0], srcs_[0], (const unsigned*)kvA[0],
                rp_[2], srcs_[2], (const unsigned*)kvA[2],
                (const unsigned*)q0, relP + (size_t)(l * 3 + 0) * H, relP + (size_t)(l * 3 + 2) * H,
                (unsigned*)aggV, NV);
            edge_agg1<0><<<(NC + 3) / 4, 256, 0, stream>>>(
                rp_[1], srcs_[1], (const unsigned*)kvA[1], (const unsigned*)q1,
                relP + (size_t)(l * 3 + 1) * H, (unsigned*)aggC, NC);
        } else {
            // q projections
            {
                WArr<1> j; j.j[0] = {wt_q(l, 0), qb + (l * 2 + 0) * C, q0, C};
                mgemmN<1, 1, 0, 0><<<grid_of(NV), 256, 0, stream>>>(xs0, j, nullptr, nullptr, NV);
                WArr<1> k; k.j[0] = {wt_q(l, 1), qb + (l * 2 + 1) * C, q1, C};
                mgemmN<1, 1, 0, 0><<<grid_of(NC), 256, 0, stream>>>(xs1, k, nullptr, nullptr, NC);
            }
            for (int e = 0; e < 3; ++e) {
                const int st = est[e], dt = edt[e];
                const ushort_t* xsrc = st ? xs1 : xs0;
                const int Ns = Nsrel[e];
                const int Nd = Ndrel[e];
                const int le = l * 3 + e;
                WArr<2> j;
                j.j[0] = {wt_f(le, 0), fb(le, 0), kvB, 2 * C};
                j.j[1] = {wt_f(le, 1), fb(le, 1), kvB + C, 2 * C};
                mgemmN<2, 1, 0, 0><<<grid_of(Ns), 256, 0, stream>>>(xsrc, j, nullptr, nullptr, Ns);
                const unsigned* qv = (const unsigned*)(dt ? q1 : q0);
                unsigned* agg_d = (unsigned*)(dt ? aggC : aggV);
                const float* rpp = relP + (size_t)le * H;
                if (e == 2)
                    edge_agg1<1><<<(Nd + 3) / 4, 256, 0, stream>>>(rp_[e], srcs_[e], (const unsigned*)kvB, qv, rpp, agg_d, Nd);
                else
                    edge_agg1<0><<<(Nd + 3) / 4, 256, 0, stream>>>(rp_[e], srcs_[e], (const unsigned*)kvB, qv, rpp, agg_d, Nd);
            }
        }

        // node update: x = g*(gelu(agg) @ aW + ab) + (1-g)*x
        {
            WArr<1> j; j.j[0] = {wt_a(l, 0), ab + (l * 2 + 0) * C, xs0, C};
            mgemmN<1, 1, 1, 2><<<grid_of(NV), 256, 0, stream>>>(aggV, j, xs0, skip + (l * 2 + 0), NV);
            WArr<1> k; k.j[0] = {wt_a(l, 1), ab + (l * 2 + 1) * C, xs1, C};
            mgemmN<1, 1, 1, 2><<<grid_of(NC), 256, 0, stream>>>(aggC, k, xs1, skip + (l * 2 + 1), NC);
        }
    }

    // 5) last visit per patient @ linW + linb
    final_lin<<<B, 128, 0, stream>>>(xs0, slices, linW, linb, (float*)d_out);
}

// Round 6
// 1336.675 us; speedup vs baseline: 7.5223x; 1.0703x over previous
//
#include <hip/hip_runtime.h>
#include <math.h>

#define H 4
#define D 32
#define C 128
#define CC (C * C)
#define SC 2048
#define SHST 68   // LDS row stride (shorts) for epilogue staging

typedef unsigned short ushort_t;
typedef __attribute__((ext_vector_type(8))) short bf16x8;
typedef __attribute__((ext_vector_type(4))) float f32x4;

union BF8 { bf16x8 v; ushort_t u[8]; };

// ---------- helpers ----------
__device__ __forceinline__ float bf2f(ushort_t u) {
    return __uint_as_float(((unsigned)u) << 16);
}
__device__ __forceinline__ ushort_t f2bf(float f) {
    unsigned u = __float_as_uint(f);
    u += 0x7fffu + ((u >> 16) & 1u);
    return (ushort_t)(u >> 16);
}
__device__ __forceinline__ void unpack2(unsigned w, float& a, float& b) {
    a = __uint_as_float(w << 16);
    b = __uint_as_float(w & 0xffff0000u);
}
__device__ __forceinline__ unsigned pack2(float a, float b) {
    return ((unsigned)f2bf(b) << 16) | (unsigned)f2bf(a);
}
__device__ __forceinline__ float gelu_t(float x) {
    float z = 0.7978845608028654f * (x + 0.044715f * x * x * x);
    float t = 1.0f - 2.0f / (__expf(2.0f * z) + 1.0f);
    return 0.5f * x * (1.0f + t);
}

// ---------- diag ----------
__global__ void diag_fill(float* out, int n, float v) {
    int i = blockIdx.x * 256 + threadIdx.x;
    if (i < n) out[i] = v;
}

// ---------- fused relation weights (fp32): W' = W @ blockdiag(rel) ----------
__global__ void fuse_weights(const float* __restrict__ kW, const float* __restrict__ kb,
                             const float* __restrict__ vW, const float* __restrict__ vb,
                             const float* __restrict__ relA, const float* __restrict__ relM,
                             float* __restrict__ fw)
{
    int bid = blockIdx.x;      // 0..11
    int le = bid >> 1;         // l*3+e
    int which = bid & 1;       // 0 = k/relA, 1 = v/relM
    int l = le / 3, e = le % 3;
    const int est[3] = {1, 0, 0};
    int st = est[e];
    const float* Wsrc = (which ? vW : kW) + (size_t)(l * 2 + st) * CC;
    const float* bsrc = (which ? vb : kb) + (size_t)(l * 2 + st) * C;
    const float* rel  = (which ? relM : relA) + (size_t)(l * 3 + e) * H * D * D;
    float* out = fw + (size_t)(le * 2 + which) * (CC + C);

    __shared__ float rsh[H * D * D];
    for (int i = threadIdx.x; i < H * D * D; i += 256) rsh[i] = rel[i];
    __syncthreads();

    for (int i = threadIdx.x; i < CC; i += 256) {
        int c = i >> 7, hf = i & 127, h = hf >> 5, f = hf & 31;
        float acc = 0.f;
        #pragma unroll
        for (int d = 0; d < D; ++d)
            acc += Wsrc[c * C + h * D + d] * rsh[h * D * D + d * D + f];
        out[i] = acc;
    }
    for (int i = threadIdx.x; i < C; i += 256) {
        int h = i >> 5, f = i & 31;
        float acc = 0.f;
        #pragma unroll
        for (int d = 0; d < D; ++d)
            acc += bsrc[h * D + d] * rsh[h * D * D + d * D + f];
        out[CC + i] = acc;
    }
}

// ---------- transpose all weights to bf16 Wt[n][k] (k contiguous) ----------
__global__ void trans_w(const float* __restrict__ lin0_W, const float* __restrict__ qW,
                        const float* __restrict__ aW, const float* __restrict__ fw,
                        ushort_t* __restrict__ wt)
{
    int id = blockIdx.x;
    const float* src;
    if (id < 2)       src = lin0_W + (size_t)id * CC;
    else if (id < 6)  src = qW + (size_t)(id - 2) * CC;
    else if (id < 10) src = aW + (size_t)(id - 6) * CC;
    else              src = fw + (size_t)(id - 10) * (CC + C);
    ushort_t* dst = wt + (size_t)id * CC;
    for (int i = threadIdx.x; i < CC; i += 256) {
        int n = i >> 7, k = i & 127;
        dst[i] = f2bf(src[k * C + n]);
    }
}

// ---------- multi-weight MFMA GEMM: Y_w = [N,128]@Wt_w^T + b_w for w<NW ----------
struct WJob { const ushort_t* w; const float* b; ushort_t* y; int ystride; };
template <int NW> struct WArr { WJob j[NW]; };

// INTYPE: 0 = f32 X, 1 = bf16 X.  PRE: 1 = gelu on X.  POST: 1 = relu, 2 = blend with Old
template <int NW, int INTYPE, int PRE, int POST>
__global__ __launch_bounds__(256, 4) void mgemmN(
    const void* __restrict__ Xv, WArr<NW> W,
    const ushort_t* __restrict__ Oldv, const float* __restrict__ skipp, int N)
{
    __shared__ ushort_t sh[4][32 * SHST];   // per-wave 32x64 output staging

    const int wave = threadIdx.x >> 6, lane = threadIdx.x & 63;
    const int wr = wave >> 1, wc = wave & 1;
    const int lr = lane & 15, lk = lane >> 4;
    const int rr2 = lane >> 4;      // read-back: row within 4-row group
    const int c4 = lane & 15;       // read-back: 4-short column chunk

    float g = 0.f;
    if (POST == 2) g = 1.0f / (1.0f + __expf(-skipp[0]));

    const int tiles = (N + 63) >> 6;
    for (int t = blockIdx.x; t < tiles; t += gridDim.x) {
        const int rbase = (t << 6) + wr * 32;
        // hold full-K A fragments in registers (reused across all NW weights)
        BF8 a[2][4];
        #pragma unroll
        for (int m = 0; m < 2; ++m) {
            const int r = rbase + m * 16 + lr;
            if (INTYPE == 0) {
                #pragma unroll
                for (int kk = 0; kk < 4; ++kk) {
                    float vv[8];
                    if (r < N) {
                        const float* p = (const float*)Xv + (size_t)r * C + kk * 32 + lk * 8;
                        float4 u0 = *(const float4*)p;
                        float4 u1 = *(const float4*)(p + 4);
                        vv[0] = u0.x; vv[1] = u0.y; vv[2] = u0.z; vv[3] = u0.w;
                        vv[4] = u1.x; vv[5] = u1.y; vv[6] = u1.z; vv[7] = u1.w;
                    } else {
                        #pragma unroll
                        for (int jj = 0; jj < 8; ++jj) vv[jj] = 0.f;
                    }
                    #pragma unroll
                    for (int jj = 0; jj < 8; ++jj) a[m][kk].u[jj] = f2bf(PRE ? gelu_t(vv[jj]) : vv[jj]);
                }
            } else {
                #pragma unroll
                for (int kk = 0; kk < 4; ++kk) {
                    if (r < N) {
                        a[m][kk].v = *(const bf16x8*)((const ushort_t*)Xv + (size_t)r * C + kk * 32 + lk * 8);
                        if (PRE) {
                            #pragma unroll
                            for (int jj = 0; jj < 8; ++jj) a[m][kk].u[jj] = f2bf(gelu_t(bf2f(a[m][kk].u[jj])));
                        }
                    } else {
                        #pragma unroll
                        for (int jj = 0; jj < 8; ++jj) a[m][kk].u[jj] = 0;
                    }
                }
            }
        }

        #pragma unroll
        for (int w = 0; w < NW; ++w) {
            const ushort_t* Wt = W.j[w].w;
            f32x4 acc[2][4];
            #pragma unroll
            for (int m = 0; m < 2; ++m)
                #pragma unroll
                for (int n = 0; n < 4; ++n)
                    acc[m][n] = (f32x4){0.f, 0.f, 0.f, 0.f};

            #pragma unroll
            for (int kk = 0; kk < 4; ++kk) {
                #pragma unroll
                for (int n = 0; n < 4; ++n) {
                    BF8 b;
                    b.v = *(const bf16x8*)(Wt + (size_t)(wc * 64 + n * 16 + lr) * C + kk * 32 + lk * 8);
                    acc[0][n] = __builtin_amdgcn_mfma_f32_16x16x32_bf16(a[0][kk].v, b.v, acc[0][n], 0, 0, 0);
                    acc[1][n] = __builtin_amdgcn_mfma_f32_16x16x32_bf16(a[1][kk].v, b.v, acc[1][n], 0, 0, 0);
                }
            }

            const float* bias = W.j[w].b;
            float bcol[4];
            #pragma unroll
            for (int n = 0; n < 4; ++n) bcol[n] = bias[wc * 64 + n * 16 + lr];

            // stage epilogue'd tile to LDS (bank-conflict-free: stride 68 shorts)
            #pragma unroll
            for (int m = 0; m < 2; ++m) {
                #pragma unroll
                for (int reg = 0; reg < 4; ++reg) {
                    const int wrow = m * 16 + lk * 4 + reg;
                    #pragma unroll
                    for (int n = 0; n < 4; ++n) {
                        float y = acc[m][n][reg] + bcol[n];
                        if (POST == 1) y = fmaxf(y, 0.f);
                        sh[wave][wrow * SHST + n * 16 + lr] = f2bf(y);
                    }
                }
            }

            // read back 8B/lane, blend if needed, coalesced store (4 rows x 128B per inst)
            ushort_t* Y = W.j[w].y;
            const int ystride = W.j[w].ystride;
            #pragma unroll
            for (int i2 = 0; i2 < 8; ++i2) {
                const int wrow = i2 * 4 + rr2;
                const int grow = rbase + wrow;
                if (grow < N) {
                    uint2 val = *(const uint2*)&sh[wave][wrow * SHST + c4 * 4];
                    if (POST == 2) {
                        uint2 o = *(const uint2*)(Oldv + (size_t)grow * C + wc * 64 + c4 * 4);
                        float y0, y1, o0, o1;
                        unpack2(val.x, y0, y1); unpack2(o.x, o0, o1);
                        val.x = pack2(g * y0 + (1.f - g) * o0, g * y1 + (1.f - g) * o1);
                        unpack2(val.y, y0, y1); unpack2(o.y, o0, o1);
                        val.y = pack2(g * y0 + (1.f - g) * o0, g * y1 + (1.f - g) * o1);
                    }
                    *(uint2*)(Y + (size_t)grow * ystride + wc * 64 + c4 * 4) = val;
                }
            }
        }
    }
}

// ---------- CSR build ----------
__global__ void hist_k(const int* __restrict__ ei, int E, int* __restrict__ cnt) {
    int i = blockIdx.x * 256 + threadIdx.x;
    if (i < E) atomicAdd(&cnt[ei[E + i]], 1);
}

__global__ __launch_bounds__(256) void scan1(const int* __restrict__ cnt, int n, int* __restrict__ part) {
    __shared__ int sh[256];
    int b = blockIdx.x, t = threadIdx.x;
    int base = b * SC + t * 8;
    int s = 0;
    #pragma unroll
    for (int j = 0; j < 8; ++j) { int i = base + j; if (i < n) s += cnt[i]; }
    sh[t] = s; __syncthreads();
    for (int off = 128; off > 0; off >>= 1) {
        if (t < off) sh[t] += sh[t + off];
        __syncthreads();
    }
    if (t == 0) part[b] = sh[0];
}

__global__ void scan2(int* part, int nb) {
    if (threadIdx.x == 0 && blockIdx.x == 0) {
        int run = 0;
        for (int i = 0; i < nb; ++i) { int v = part[i]; part[i] = run; run += v; }
        part[nb] = run;
    }
}

__global__ __launch_bounds__(256) void scan3(const int* __restrict__ cnt, int n,
                                             const int* __restrict__ part, int* __restrict__ rowptr) {
    __shared__ int sh[256];
    int b = blockIdx.x, t = threadIdx.x;
    int base = b * SC + t * 8;
    int loc[8]; int s = 0;
    #pragma unroll
    for (int j = 0; j < 8; ++j) { int i = base + j; int v = (i < n) ? cnt[i] : 0; s += v; loc[j] = s; }
    sh[t] = s; __syncthreads();
    for (int off = 1; off < 256; off <<= 1) {
        int v = (t >= off) ? sh[t - off] : 0;
        __syncthreads();
        sh[t] += v;
        __syncthreads();
    }
    int excl = (t ? sh[t - 1] : 0) + part[b];
    #pragma unroll
    for (int j = 0; j < 8; ++j) { int i = base + j; if (i < n) rowptr[i + 1] = excl + loc[j]; }
    if (b == 0 && t == 0) rowptr[0] = 0;
}

__global__ void scatter_k(const int* __restrict__ ei, int E, int* __restrict__ wp, int* __restrict__ srcs) {
    int i = blockIdx.x * 256 + threadIdx.x;
    if (i < E) {
        int pos = atomicAdd(&wp[ei[E + i]], 1);
        srcs[pos] = ei[i];
    }
}

// ---------- one relation's softmax-weighted accumulation (2-way unrolled) ----------
__device__ __forceinline__ void rel_accum(
    const int* __restrict__ rowptr, const int* __restrict__ srcs, const unsigned* __restrict__ kv,
    int wid, int lane, float q0, float q1, float rp, float& out0, float& out1)
{
    int beg = rowptr[wid], end = rowptr[wid + 1];
    float denom = 0.f, a0 = 0.f, a1 = 0.f;
    int i = beg;
    for (; i + 2 <= end; i += 2) {
        int sA = srcs[i], sB = srcs[i + 1];
        const unsigned* rA = kv + (size_t)sA * 128;
        const unsigned* rB = kv + (size_t)sB * 128;
        unsigned kA = rA[lane], kB = rB[lane];
        unsigned vA = rA[64 + lane], vB = rB[64 + lane];
        float kA0, kA1, kB0, kB1;
        unpack2(kA, kA0, kA1); unpack2(kB, kB0, kB1);
        float dpA = kA0 * q0 + kA1 * q1;
        float dpB = kB0 * q0 + kB1 * q1;
        dpA += __shfl_xor(dpA, 1, 16); dpB += __shfl_xor(dpB, 1, 16);
        dpA += __shfl_xor(dpA, 2, 16); dpB += __shfl_xor(dpB, 2, 16);
        dpA += __shfl_xor(dpA, 4, 16); dpB += __shfl_xor(dpB, 4, 16);
        dpA += __shfl_xor(dpA, 8, 16); dpB += __shfl_xor(dpB, 8, 16);
        float wA = __expf(dpA * rp), wB = __expf(dpB * rp);
        float vA0, vA1, vB0, vB1;
        unpack2(vA, vA0, vA1); unpack2(vB, vB0, vB1);
        denom += wA + wB;
        a0 += wA * vA0 + wB * vB0;
        a1 += wA * vA1 + wB * vB1;
    }
    if (i < end) {
        const unsigned* r = kv + (size_t)srcs[i] * 128;
        unsigned k2 = r[lane], v2 = r[64 + lane];
        float k0, k1, v0, v1;
        unpack2(k2, k0, k1); unpack2(v2, v0, v1);
        float dp = k0 * q0 + k1 * q1;
        dp += __shfl_xor(dp, 1, 16);
        dp += __shfl_xor(dp, 2, 16);
        dp += __shfl_xor(dp, 4, 16);
        dp += __shfl_xor(dp, 8, 16);
        float w = __expf(dp * rp);
        denom += w; a0 += w * v0; a1 += w * v1;
    }
    float r = 1.0f / (denom + 1e-16f);
    out0 += a0 * r; out1 += a1 * r;
}

// ---------- per-node attention aggregate, single relation ----------
template <int ACCUM>
__global__ __launch_bounds__(256) void edge_agg1(
    const int* __restrict__ rowptr, const int* __restrict__ srcs,
    const unsigned* __restrict__ kv, const unsigned* __restrict__ qv,
    const float* __restrict__ relP, unsigned* __restrict__ agg, int Nd)
{
    int wid = (blockIdx.x * 256 + threadIdx.x) >> 6;
    int lane = threadIdx.x & 63;
    if (wid >= Nd) return;
    unsigned q2 = qv[(size_t)wid * 64 + lane];
    float q0, q1; unpack2(q2, q0, q1);
    float rp = relP[lane >> 4] * 0.17677669529663687f;
    float out0 = 0.f, out1 = 0.f;
    rel_accum(rowptr, srcs, kv, wid, lane, q0, q1, rp, out0, out1);
    if (ACCUM) {
        unsigned o = agg[(size_t)wid * 64 + lane];
        float o0, o1; unpack2(o, o0, o1);
        out0 += o0; out1 += o1;
    }
    agg[(size_t)wid * 64 + lane] = pack2(out0, out1);
}

// ---------- merged: two relations into one dst set (visits: e=0 and e=2) ----------
__global__ __launch_bounds__(256) void edge_agg2(
    const int* __restrict__ rp0, const int* __restrict__ s0, const unsigned* __restrict__ kv0,
    const int* __restrict__ rp2, const int* __restrict__ s2, const unsigned* __restrict__ kv2,
    const unsigned* __restrict__ qv, const float* __restrict__ relP0, const float* __restrict__ relP2,
    unsigned* __restrict__ agg, int Nd)
{
    int wid = (blockIdx.x * 256 + threadIdx.x) >> 6;
    int lane = threadIdx.x & 63;
    if (wid >= Nd) return;
    unsigned q2 = qv[(size_t)wid * 64 + lane];
    float q0, q1; unpack2(q2, q0, q1);
    float rpA = relP0[lane >> 4] * 0.17677669529663687f;
    float rpB = relP2[lane >> 4] * 0.17677669529663687f;
    float out0 = 0.f, out1 = 0.f;
    rel_accum(rp0, s0, kv0, wid, lane, q0, q1, rpA, out0, out1);
    rel_accum(rp2, s2, kv2, wid, lane, q0, q1, rpB, out0, out1);
    agg[(size_t)wid * 64 + lane] = pack2(out0, out1);
}

// ---------- final: gather last visit per patient, @ linW + linb ----------
__global__ void final_lin(const ushort_t* __restrict__ xs0, const int* __restrict__ slices,
                          const float* __restrict__ Wl, const float* __restrict__ bl,
                          float* __restrict__ out)
{
    __shared__ float xr[C];
    int b = blockIdx.x, o = threadIdx.x;
    int row = slices[b + 1] - 1;
    xr[o] = bf2f(xs0[(size_t)row * C + o]);
    __syncthreads();
    float acc = bl[o];
    #pragma unroll 4
    for (int c = 0; c < C; ++c) acc += xr[c] * Wl[c * C + o];
    out[(size_t)b * C + o] = acc;
}

extern "C" void kernel_launch(void* const* d_in, const int* in_sizes, int n_in,
                              void* d_out, int out_size, void* d_ws, size_t ws_size,
                              hipStream_t stream)
{
    (void)n_in;
    const float* x_visit = (const float*)d_in[0];
    const float* x_code  = (const float*)d_in[1];
    const int* slices    = (const int*)d_in[5];
    const float* lin0_W  = (const float*)d_in[6];
    const float* lin0_b  = (const float*)d_in[7];
    const float* kW  = (const float*)d_in[8];
    const float* kb  = (const float*)d_in[9];
    const float* qW  = (const float*)d_in[10];
    const float* qb  = (const float*)d_in[11];
    const float* vW  = (const float*)d_in[12];
    const float* vb  = (const float*)d_in[13];
    const float* aW  = (const float*)d_in[14];
    const float* ab  = (const float*)d_in[15];
    const float* skip = (const float*)d_in[16];
    const float* relA = (const float*)d_in[17];
    const float* relM = (const float*)d_in[18];
    const float* relP = (const float*)d_in[19];
    const float* linW = (const float*)d_in[20];
    const float* linb = (const float*)d_in[21];

    const int NV = in_sizes[0] / C;
    const int NC = in_sizes[1] / C;
    const int NN = NV > NC ? NV : NC;
    const int B = in_sizes[5] - 1;

    const int est[3] = {1, 0, 0}, edt[3] = {0, 1, 0};
    const int* eptr[3] = {(const int*)d_in[2], (const int*)d_in[3], (const int*)d_in[4]};
    const int Ecnt[3] = {in_sizes[2] / 2, in_sizes[3] / 2, in_sizes[4] / 2};
    const int Ndrel[3] = {NV, NC, NV};
    const int Nsrel[3] = {NC, NV, NV};

    // ---- workspace plan: common block, then plan-A (per-relation kv) or plan-B (shared kv) ----
    size_t off = 0;
    auto AL = [&](size_t bytes) { size_t c = off; off += (bytes + 255) & ~(size_t)255; return c; };
    size_t o_xs0  = AL((size_t)NV * C * 2);
    size_t o_xs1  = AL((size_t)NC * C * 2);
    size_t o_q0   = AL((size_t)NV * C * 2);
    size_t o_q1   = AL((size_t)NC * C * 2);
    size_t o_aggV = AL((size_t)NV * C * 2);
    size_t o_aggC = AL((size_t)NC * C * 2);
    size_t o_rp[3], o_srcs[3];
    for (int e = 0; e < 3; ++e) {
        o_rp[e]   = AL(((size_t)Ndrel[e] + 1) * 4);
        o_srcs[e] = AL((size_t)Ecnt[e] * 4);
    }
    size_t o_wp   = AL(((size_t)NN + 1) * 4);
    size_t o_part = AL(4096);
    size_t o_fw   = AL((size_t)12 * (CC + C) * 4);
    size_t o_wt   = AL((size_t)22 * CC * 2);
    size_t common_end = off;

    // plan A: kv per relation
    size_t o_kvA[3];
    for (int e = 0; e < 3; ++e) o_kvA[e] = AL((size_t)Nsrel[e] * 2 * C * 2);
    size_t totalA = off;
    // plan B: one shared kv
    off = common_end;
    size_t o_kvB = AL((size_t)NN * 2 * C * 2);
    size_t totalB = off;

    int planA;
    if (ws_size >= totalA) planA = 1;
    else if (ws_size >= totalB) planA = 0;
    else {
        float v = 10.0f + (float)((double)ws_size * 1e-9);
        diag_fill<<<(out_size + 255) / 256, 256, 0, stream>>>((float*)d_out, out_size, v);
        return;
    }

    char* base = (char*)d_ws;
    ushort_t* xs0  = (ushort_t*)(base + o_xs0);
    ushort_t* xs1  = (ushort_t*)(base + o_xs1);
    ushort_t* q0   = (ushort_t*)(base + o_q0);
    ushort_t* q1   = (ushort_t*)(base + o_q1);
    ushort_t* aggV = (ushort_t*)(base + o_aggV);
    ushort_t* aggC = (ushort_t*)(base + o_aggC);
    int* rp_[3]; int* srcs_[3];
    for (int e = 0; e < 3; ++e) { rp_[e] = (int*)(base + o_rp[e]); srcs_[e] = (int*)(base + o_srcs[e]); }
    int* wp   = (int*)(base + o_wp);
    int* part = (int*)(base + o_part);
    float* fw = (float*)(base + o_fw);
    ushort_t* wt = (ushort_t*)(base + o_wt);
    ushort_t* kvA[3];
    for (int e = 0; e < 3; ++e) kvA[e] = (ushort_t*)(base + (planA ? o_kvA[e] : o_kvB));
    ushort_t* kvB = (ushort_t*)(base + o_kvB);

    auto wt_q = [&](int l, int t) { return wt + (size_t)(2 + l * 2 + t) * CC; };
    auto wt_a = [&](int l, int t) { return wt + (size_t)(6 + l * 2 + t) * CC; };
    auto wt_f = [&](int le, int which) { return wt + (size_t)(10 + le * 2 + which) * CC; };
    auto fb   = [&](int le, int which) { return fw + (size_t)(le * 2 + which) * (CC + C) + CC; };

    // 1) fused relation weights + bf16 transposed weights
    fuse_weights<<<12, 256, 0, stream>>>(kW, kb, vW, vb, relA, relM, fw);
    trans_w<<<22, 256, 0, stream>>>(lin0_W, qW, aW, fw, wt);

    auto grid_of = [](int N) { unsigned t = (unsigned)((N + 63) / 64); return t < 32768u ? t : 32768u; };

    // 2) input projection + relu (f32 in, bf16 out)
    {
        WArr<1> j; j.j[0] = {wt + 0 * CC, lin0_b, xs0, C};
        mgemmN<1, 0, 0, 1><<<grid_of(NV), 256, 0, stream>>>(x_visit, j, nullptr, nullptr, NV);
        WArr<1> k; k.j[0] = {wt + 1 * CC, lin0_b + C, xs1, C};
        mgemmN<1, 0, 0, 1><<<grid_of(NC), 256, 0, stream>>>(x_code, k, nullptr, nullptr, NC);
    }

    // 3) CSR build per relation
    for (int e = 0; e < 3; ++e) {
        int Nd = Ndrel[e], E = Ecnt[e];
        int nb = (Nd + SC - 1) / SC;
        hipMemsetAsync(wp, 0, (size_t)Nd * 4, stream);
        hist_k<<<(E + 255) / 256, 256, 0, stream>>>(eptr[e], E, wp);
        scan1<<<nb, 256, 0, stream>>>(wp, Nd, part);
        scan2<<<1, 64, 0, stream>>>(part, nb);
        scan3<<<nb, 256, 0, stream>>>(wp, Nd, part, rp_[e]);
        hipMemcpyAsync(wp, rp_[e], (size_t)Nd * 4, hipMemcpyDeviceToDevice, stream);
        scatter_k<<<(E + 255) / 256, 256, 0, stream>>>(eptr[e], E, wp, srcs_[e]);
    }

    // 4) layers
    for (int l = 0; l < 2; ++l) {
        if (planA) {
            {
                WArr<5> j;
                j.j[0] = {wt_q(l, 0), qb + (l * 2 + 0) * C, q0, C};
                j.j[1] = {wt_f(l * 3 + 1, 0), fb(l * 3 + 1, 0), kvA[1], 2 * C};
                j.j[2] = {wt_f(l * 3 + 1, 1), fb(l * 3 + 1, 1), kvA[1] + C, 2 * C};
                j.j[3] = {wt_f(l * 3 + 2, 0), fb(l * 3 + 2, 0), kvA[2], 2 * C};
                j.j[4] = {wt_f(l * 3 + 2, 1), fb(l * 3 + 2, 1), kvA[2] + C, 2 * C};
                mgemmN<5, 1, 0, 0><<<grid_of(NV), 256, 0, stream>>>(xs0, j, nullptr, nullptr, NV);
            }
            {
                WArr<3> j;
                j.j[0] = {wt_q(l, 1), qb + (l * 2 + 1) * C, q1, C};
                j.j[1] = {wt_f(l * 3 + 0, 0), fb(l * 3 + 0, 0), kvA[0], 2 * C};
                j.j[2] = {wt_f(l * 3 + 0, 1), fb(l * 3 + 0, 1), kvA[0] + C, 2 * C};
                mgemmN<3, 1, 0, 0><<<grid_of(NC), 256, 0, stream>>>(xs1, j, nullptr, nullptr, NC);
            }
            edge_agg2<<<(NV + 3) / 4, 256, 0, stream>>>(
                rp_[0], srcs_[0], (const unsigned*)kvA[0],
                rp_[2], srcs_[2], (const unsigned*)kvA[2],
                (const unsigned*)q0, relP + (size_t)(l * 3 + 0) * H, relP + (size_t)(l * 3 + 2) * H,
                (unsigned*)aggV, NV);
            edge_agg1<0><<<(NC + 3) / 4, 256, 0, stream>>>(
                rp_[1], srcs_[1], (const unsigned*)kvA[1], (const unsigned*)q1,
                relP + (size_t)(l * 3 + 1) * H, (unsigned*)aggC, NC);
        } else {
            {
                WArr<1> j; j.j[0] = {wt_q(l, 0), qb + (l * 2 + 0) * C, q0, C};
                mgemmN<1, 1, 0, 0><<<grid_of(NV), 256, 0, stream>>>(xs0, j, nullptr, nullptr, NV);
                WArr<1> k; k.j[0] = {wt_q(l, 1), qb + (l * 2 + 1) * C, q1, C};
                mgemmN<1, 1, 0, 0><<<grid_of(NC), 256, 0, stream>>>(xs1, k, nullptr, nullptr, NC);
            }
            for (int e = 0; e < 3; ++e) {
                const int st = est[e], dt = edt[e];
                const ushort_t* xsrc = st ? xs1 : xs0;
                const int Ns = Nsrel[e];
                const int Nd = Ndrel[e];
                const int le = l * 3 + e;
                WArr<2> j;
                j.j[0] = {wt_f(le, 0), fb(le, 0), kvB, 2 * C};
                j.j[1] = {wt_f(le, 1), fb(le, 1), kvB + C, 2 * C};
                mgemmN<2, 1, 0, 0><<<grid_of(Ns), 256, 0, stream>>>(xsrc, j, nullptr, nullptr, Ns);
                const unsigned* qv = (const unsigned*)(dt ? q1 : q0);
                unsigned* agg_d = (unsigned*)(dt ? aggC : aggV);
                const float* rpp = relP + (size_t)le * H;
                if (e == 2)
                    edge_agg1<1><<<(Nd + 3) / 4, 256, 0, stream>>>(rp_[e], srcs_[e], (const unsigned*)kvB, qv, rpp, agg_d, Nd);
                else
                    edge_agg1<0><<<(Nd + 3) / 4, 256, 0, stream>>>(rp_[e], srcs_[e], (const unsigned*)kvB, qv, rpp, agg_d, Nd);
            }
        }

        // node update: x = g*(gelu(agg) @ aW + ab) + (1-g)*x
        {
            WArr<1> j; j.j[0] = {wt_a(l, 0), ab + (l * 2 + 0) * C, xs0, C};
            mgemmN<1, 1, 1, 2><<<grid_of(NV), 256, 0, stream>>>(aggV, j, xs0, skip + (l * 2 + 0), NV);
            WArr<1> k; k.j[0] = {wt_a(l, 1), ab + (l * 2 + 1) * C, xs1, C};
            mgemmN<1, 1, 1, 2><<<grid_of(NC), 256, 0, stream>>>(aggC, k, xs1, skip + (l * 2 + 1), NC);
        }
    }

    // 5) last visit per patient @ linW + linb
    final_lin<<<B, 128, 0, stream>>>(xs0, slices, linW, linb, (float*)d_out);
}

// Round 11
// 1253.747 us; speedup vs baseline: 8.0198x; 1.0661x over previous
//
#include <hip/hip_runtime.h>
#include <math.h>

#define H 4
#define D 32
#define C 128
#define CC (C * C)
#define SC 2048
#define LST 136   // LDS row stride (shorts); 272B = multiple of 16 -> aligned b128 reads
#define SHST 68
#define RSC 0.17677669529663687f

typedef unsigned short ushort_t;
typedef __attribute__((ext_vector_type(8))) short bf16x8;
typedef __attribute__((ext_vector_type(4))) float f32x4;

union BF8 { bf16x8 v; ushort_t u[8]; };

// ---------- helpers ----------
__device__ __forceinline__ float bf2f(ushort_t u) {
    return __uint_as_float(((unsigned)u) << 16);
}
__device__ __forceinline__ ushort_t f2bf(float f) {
    unsigned u = __float_as_uint(f);
    u += 0x7fffu + ((u >> 16) & 1u);
    return (ushort_t)(u >> 16);
}
__device__ __forceinline__ void unpack2(unsigned w, float& a, float& b) {
    a = __uint_as_float(w << 16);
    b = __uint_as_float(w & 0xffff0000u);
}
__device__ __forceinline__ unsigned pack2(float a, float b) {
    return ((unsigned)f2bf(b) << 16) | (unsigned)f2bf(a);
}
__device__ __forceinline__ float gelu_t(float x) {
    float z = 0.7978845608028654f * (x + 0.044715f * x * x * x);
    float t = 1.0f - 2.0f / (__expf(2.0f * z) + 1.0f);
    return 0.5f * x * (1.0f + t);
}

// ---------- diag ----------
__global__ void diag_fill(float* out, int n, float v) {
    int i = blockIdx.x * 256 + threadIdx.x;
    if (i < n) out[i] = v;
}

// ---------- fused relation weights (fp32): W' = W @ blockdiag(rel) ----------
__global__ void fuse_weights(const float* __restrict__ kW, const float* __restrict__ kb,
                             const float* __restrict__ vW, const float* __restrict__ vb,
                             const float* __restrict__ relA, const float* __restrict__ relM,
                             float* __restrict__ fw)
{
    int bid = blockIdx.x;      // 0..11
    int le = bid >> 1;         // l*3+e
    int which = bid & 1;       // 0 = k/relA, 1 = v/relM
    int l = le / 3, e = le % 3;
    const int est[3] = {1, 0, 0};
    int st = est[e];
    const float* Wsrc = (which ? vW : kW) + (size_t)(l * 2 + st) * CC;
    const float* bsrc = (which ? vb : kb) + (size_t)(l * 2 + st) * C;
    const float* rel  = (which ? relM : relA) + (size_t)(l * 3 + e) * H * D * D;
    float* out = fw + (size_t)(le * 2 + which) * (CC + C);

    __shared__ float rsh[H * D * D];
    for (int i = threadIdx.x; i < H * D * D; i += 256) rsh[i] = rel[i];
    __syncthreads();

    for (int i = threadIdx.x; i < CC; i += 256) {
        int c = i >> 7, hf = i & 127, h = hf >> 5, f = hf & 31;
        float acc = 0.f;
        #pragma unroll
        for (int d = 0; d < D; ++d)
            acc += Wsrc[c * C + h * D + d] * rsh[h * D * D + d * D + f];
        out[i] = acc;
    }
    for (int i = threadIdx.x; i < C; i += 256) {
        int h = i >> 5, f = i & 31;
        float acc = 0.f;
        #pragma unroll
        for (int d = 0; d < D; ++d)
            acc += bsrc[h * D + d] * rsh[h * D * D + d * D + f];
        out[CC + i] = acc;
    }
}

// ---------- transpose all weights to bf16 Wt[n][k] ----------
__global__ void trans_w(const float* __restrict__ lin0_W, const float* __restrict__ qW,
                        const float* __restrict__ aW, const float* __restrict__ fw,
                        ushort_t* __restrict__ wt)
{
    int id = blockIdx.x;
    const float* src;
    if (id < 2)       src = lin0_W + (size_t)id * CC;
    else if (id < 6)  src = qW + (size_t)(id - 2) * CC;
    else if (id < 10) src = aW + (size_t)(id - 6) * CC;
    else              src = fw + (size_t)(id - 10) * (CC + C);
    ushort_t* dst = wt + (size_t)id * CC;
    for (int i = threadIdx.x; i < CC; i += 256) {
        int n = i >> 7, k = i & 127;
        dst[i] = f2bf(src[k * C + n]);
    }
}

// ---------- fused two-stage MFMA kernel ----------
struct WJob { const ushort_t* w; const float* b; ushort_t* y; int ystride; };
struct FusedArgs {
    const void* X; const ushort_t* W1; const float* b1; ushort_t* Y1;
    const ushort_t* Old; const float* skipp; int N; int nw;
    WJob j[3];
};

// GEMM1: Y1 = post(X @ W1^T + b1); chain: for w<nw, Y_w = Y1 @ Wt_w^T + b_w (from LDS).
template <int INTYPE, int PRE, int POST>
__global__ __launch_bounds__(256, 4) void fusedProj(FusedArgs A0, FusedArgs A1, int tiles0)
{
    __shared__ ushort_t lds[64 * LST];   // 17408 B
    const bool sel0 = ((int)blockIdx.x < tiles0);
    const FusedArgs& A = sel0 ? A0 : A1;
    const int t = sel0 ? (int)blockIdx.x : (int)blockIdx.x - tiles0;
    const int N = A.N;
    const int wave = threadIdx.x >> 6, lane = threadIdx.x & 63;
    const int wr = wave >> 1, wc = wave & 1;
    const int lr = lane & 15, lk = lane >> 4;
    const int row0 = t << 6;
    const int rbase = row0 + wr * 32;

    BF8 a[2][4];
    #pragma unroll
    for (int m = 0; m < 2; ++m) {
        const int r = rbase + m * 16 + lr;
        #pragma unroll
        for (int kk = 0; kk < 4; ++kk) {
            if (INTYPE == 0) {
                float vv[8];
                if (r < N) {
                    const float* p = (const float*)A.X + (size_t)r * C + kk * 32 + lk * 8;
                    float4 u0 = *(const float4*)p;
                    float4 u1 = *(const float4*)(p + 4);
                    vv[0] = u0.x; vv[1] = u0.y; vv[2] = u0.z; vv[3] = u0.w;
                    vv[4] = u1.x; vv[5] = u1.y; vv[6] = u1.z; vv[7] = u1.w;
                } else {
                    #pragma unroll
                    for (int q = 0; q < 8; ++q) vv[q] = 0.f;
                }
                #pragma unroll
                for (int q = 0; q < 8; ++q) a[m][kk].u[q] = f2bf(PRE ? gelu_t(vv[q]) : vv[q]);
            } else {
                if (r < N) {
                    a[m][kk].v = *(const bf16x8*)((const ushort_t*)A.X + (size_t)r * C + kk * 32 + lk * 8);
                    if (PRE) {
                        #pragma unroll
                        for (int q = 0; q < 8; ++q) a[m][kk].u[q] = f2bf(gelu_t(bf2f(a[m][kk].u[q])));
                    }
                } else {
                    #pragma unroll
                    for (int q = 0; q < 8; ++q) a[m][kk].u[q] = 0;
                }
            }
        }
    }

    // ---- GEMM1 ----
    {
        f32x4 acc[2][4];
        #pragma unroll
        for (int m = 0; m < 2; ++m)
            #pragma unroll
            for (int n = 0; n < 4; ++n)
                acc[m][n] = (f32x4){0.f, 0.f, 0.f, 0.f};

        #pragma unroll
        for (int kk = 0; kk < 4; ++kk) {
            #pragma unroll
            for (int n = 0; n < 4; ++n) {
                BF8 b;
                b.v = *(const bf16x8*)(A.W1 + (size_t)(wc * 64 + n * 16 + lr) * C + kk * 32 + lk * 8);
                acc[0][n] = __builtin_amdgcn_mfma_f32_16x16x32_bf16(a[0][kk].v, b.v, acc[0][n], 0, 0, 0);
                acc[1][n] = __builtin_amdgcn_mfma_f32_16x16x32_bf16(a[1][kk].v, b.v, acc[1][n], 0, 0, 0);
            }
        }

        float bc[4];
        #pragma unroll
        for (int n = 0; n < 4; ++n) bc[n] = A.b1[wc * 64 + n * 16 + lr];
        #pragma unroll
        for (int m = 0; m < 2; ++m) {
            #pragma unroll
            for (int reg = 0; reg < 4; ++reg) {
                const int wrow = wr * 32 + m * 16 + lk * 4 + reg;
                #pragma unroll
                for (int n = 0; n < 4; ++n) {
                    float y = acc[m][n][reg] + bc[n];
                    if (POST == 1) y = fmaxf(y, 0.f);
                    lds[wrow * LST + wc * 64 + n * 16 + lr] = f2bf(y);
                }
            }
        }
    }
    __syncthreads();

    // ---- read-back: blend (POST==2) + coalesced Y1 store; blended values written back to LDS ----
    {
        float g = 0.f;
        if (POST == 2) g = 1.0f / (1.0f + __expf(-A.skipp[0]));
        #pragma unroll
        for (int it = 0; it < 8; ++it) {
            int idx = it * 256 + threadIdx.x;   // 0..2047: row=idx>>5, uint2 col=idx&31
            int row = idx >> 5, c8 = idx & 31;
            int grow = row0 + row;
            if (grow < N) {
                uint2 val = *(const uint2*)&lds[row * LST + c8 * 4];
                if (POST == 2) {
                    uint2 o = *(const uint2*)(A.Old + (size_t)grow * C + c8 * 4);
                    float y0, y1, o0, o1;
                    unpack2(val.x, y0, y1); unpack2(o.x, o0, o1);
                    val.x = pack2(g * y0 + (1.f - g) * o0, g * y1 + (1.f - g) * o1);
                    unpack2(val.y, y0, y1); unpack2(o.y, o0, o1);
                    val.y = pack2(g * y0 + (1.f - g) * o0, g * y1 + (1.f - g) * o1);
                    *(uint2*)&lds[row * LST + c8 * 4] = val;
                }
                *(uint2*)(A.Y1 + (size_t)grow * C + c8 * 4) = val;
            }
        }
    }
    __syncthreads();

    if (A.nw == 0) return;

    BF8 a2[2][4];
    #pragma unroll
    for (int m = 0; m < 2; ++m)
        #pragma unroll
        for (int kk = 0; kk < 4; ++kk)
            a2[m][kk].v = *(const bf16x8*)&lds[(wr * 32 + m * 16 + lr) * LST + kk * 32 + lk * 8];

    for (int w = 0; w < A.nw; ++w) {
        const ushort_t* Wt = A.j[w].w;
        f32x4 c2[2][4];
        #pragma unroll
        for (int m = 0; m < 2; ++m)
            #pragma unroll
            for (int n = 0; n < 4; ++n)
                c2[m][n] = (f32x4){0.f, 0.f, 0.f, 0.f};

        #pragma unroll
        for (int kk = 0; kk < 4; ++kk) {
            #pragma unroll
            for (int n = 0; n < 4; ++n) {
                BF8 b;
                b.v = *(const bf16x8*)(Wt + (size_t)(wc * 64 + n * 16 + lr) * C + kk * 32 + lk * 8);
                c2[0][n] = __builtin_amdgcn_mfma_f32_16x16x32_bf16(a2[0][kk].v, b.v, c2[0][n], 0, 0, 0);
                c2[1][n] = __builtin_amdgcn_mfma_f32_16x16x32_bf16(a2[1][kk].v, b.v, c2[1][n], 0, 0, 0);
            }
        }
        float bc[4];
        #pragma unroll
        for (int n = 0; n < 4; ++n) bc[n] = A.j[w].b[wc * 64 + n * 16 + lr];

        __syncthreads();
        #pragma unroll
        for (int m = 0; m < 2; ++m) {
            #pragma unroll
            for (int reg = 0; reg < 4; ++reg) {
                const int wrow = wr * 32 + m * 16 + lk * 4 + reg;
                #pragma unroll
                for (int n = 0; n < 4; ++n)
                    lds[wrow * LST + wc * 64 + n * 16 + lr] = f2bf(c2[m][n][reg] + bc[n]);
            }
        }
        __syncthreads();

        ushort_t* Y = A.j[w].y;
        const int ys = A.j[w].ystride;
        #pragma unroll
        for (int it = 0; it < 8; ++it) {
            int idx = it * 256 + threadIdx.x;
            int row = idx >> 5, c8 = idx & 31;
            int grow = row0 + row;
            if (grow < N) {
                uint2 val = *(const uint2*)&lds[row * LST + c8 * 4];
                *(uint2*)(Y + (size_t)grow * ys + c8 * 4) = val;
            }
        }
    }
}

// ---------- proven round-6 dual-GEMM (for the deferred kv1 projection) ----------
__global__ __launch_bounds__(256, 4) void proj2(
    const ushort_t* __restrict__ Xv,
    const ushort_t* __restrict__ WtA, const float* __restrict__ biasA,
    const ushort_t* __restrict__ WtB, const float* __restrict__ biasB,
    ushort_t* __restrict__ YA, ushort_t* __restrict__ YB, int N)
{
    __shared__ ushort_t sh[4][32 * SHST];
    const int wave = threadIdx.x >> 6, lane = threadIdx.x & 63;
    const int wr = wave >> 1, wc = wave & 1;
    const int lr = lane & 15, lk = lane >> 4;
    const int rr2 = lane >> 4, c4 = lane & 15;

    const int tiles = (N + 63) >> 6;
    for (int t = blockIdx.x; t < tiles; t += gridDim.x) {
        const int rbase = (t << 6) + wr * 32;
        BF8 a[2][4];
        #pragma unroll
        for (int m = 0; m < 2; ++m) {
            const int r = rbase + m * 16 + lr;
            #pragma unroll
            for (int kk = 0; kk < 4; ++kk) {
                if (r < N) {
                    a[m][kk].v = *(const bf16x8*)(Xv + (size_t)r * C + kk * 32 + lk * 8);
                } else {
                    #pragma unroll
                    for (int q = 0; q < 8; ++q) a[m][kk].u[q] = 0;
                }
            }
        }
        #pragma unroll
        for (int w = 0; w < 2; ++w) {
            const ushort_t* Wt = w ? WtB : WtA;
            const float* bias = w ? biasB : biasA;
            ushort_t* Y = w ? YB : YA;
            f32x4 acc[2][4];
            #pragma unroll
            for (int m = 0; m < 2; ++m)
                #pragma unroll
                for (int n = 0; n < 4; ++n)
                    acc[m][n] = (f32x4){0.f, 0.f, 0.f, 0.f};
            #pragma unroll
            for (int kk = 0; kk < 4; ++kk) {
                #pragma unroll
                for (int n = 0; n < 4; ++n) {
                    BF8 b;
                    b.v = *(const bf16x8*)(Wt + (size_t)(wc * 64 + n * 16 + lr) * C + kk * 32 + lk * 8);
                    acc[0][n] = __builtin_amdgcn_mfma_f32_16x16x32_bf16(a[0][kk].v, b.v, acc[0][n], 0, 0, 0);
                    acc[1][n] = __builtin_amdgcn_mfma_f32_16x16x32_bf16(a[1][kk].v, b.v, acc[1][n], 0, 0, 0);
                }
            }
            float bc[4];
            #pragma unroll
            for (int n = 0; n < 4; ++n) bc[n] = bias[wc * 64 + n * 16 + lr];
            #pragma unroll
            for (int m = 0; m < 2; ++m) {
                #pragma unroll
                for (int reg = 0; reg < 4; ++reg) {
                    const int wrow = m * 16 + lk * 4 + reg;
                    #pragma unroll
                    for (int n = 0; n < 4; ++n)
                        sh[wave][wrow * SHST + n * 16 + lr] = f2bf(acc[m][n][reg] + bc[n]);
                }
            }
            #pragma unroll
            for (int i2 = 0; i2 < 8; ++i2) {
                const int wrow = i2 * 4 + rr2;
                const int grow = rbase + wrow;
                if (grow < N) {
                    uint2 val = *(const uint2*)&sh[wave][wrow * SHST + c4 * 4];
                    *(uint2*)(Y + (size_t)grow * (2 * C) + wc * 64 + c4 * 4) = val;
                }
            }
        }
    }
}

// ---------- CSR build ----------
__global__ void hist_k(const int* __restrict__ ei, int E, int* __restrict__ cnt) {
    int i = blockIdx.x * 256 + threadIdx.x;
    if (i < E) atomicAdd(&cnt[ei[E + i]], 1);
}

__global__ __launch_bounds__(256) void scan1(const int* __restrict__ cnt, int n, int* __restrict__ part) {
    __shared__ int sh[256];
    int b = blockIdx.x, t = threadIdx.x;
    int base = b * SC + t * 8;
    int s = 0;
    #pragma unroll
    for (int j = 0; j < 8; ++j) { int i = base + j; if (i < n) s += cnt[i]; }
    sh[t] = s; __syncthreads();
    for (int off = 128; off > 0; off >>= 1) {
        if (t < off) sh[t] += sh[t + off];
        __syncthreads();
    }
    if (t == 0) part[b] = sh[0];
}

__global__ void scan2(int* part, int nb) {
    if (threadIdx.x == 0 && blockIdx.x == 0) {
        int run = 0;
        for (int i = 0; i < nb; ++i) { int v = part[i]; part[i] = run; run += v; }
        part[nb] = run;
    }
}

__global__ __launch_bounds__(256) void scan3(const int* __restrict__ cnt, int n,
                                             const int* __restrict__ part, int* __restrict__ rowptr) {
    __shared__ int sh[256];
    int b = blockIdx.x, t = threadIdx.x;
    int base = b * SC + t * 8;
    int loc[8]; int s = 0;
    #pragma unroll
    for (int j = 0; j < 8; ++j) { int i = base + j; int v = (i < n) ? cnt[i] : 0; s += v; loc[j] = s; }
    sh[t] = s; __syncthreads();
    for (int off = 1; off < 256; off <<= 1) {
        int v = (t >= off) ? sh[t - off] : 0;
        __syncthreads();
        sh[t] += v;
        __syncthreads();
    }
    int excl = (t ? sh[t - 1] : 0) + part[b];
    #pragma unroll
    for (int j = 0; j < 8; ++j) { int i = base + j; if (i < n) rowptr[i + 1] = excl + loc[j]; }
    if (b == 0 && t == 0) rowptr[0] = 0;
}

__global__ void scatter_k(const int* __restrict__ ei, int E, int* __restrict__ wp, int* __restrict__ srcs) {
    int i = blockIdx.x * 256 + threadIdx.x;
    if (i < E) {
        int pos = atomicAdd(&wp[ei[E + i]], 1);
        srcs[pos] = ei[i];
    }
}

// ---------- 32-lane (4 ch/lane) relation accumulate, 2-way edge unrolled ----------
__device__ __forceinline__ void rel_accum32(
    const int* __restrict__ rowptr, const int* __restrict__ srcs, const unsigned* __restrict__ kv,
    int nid, int j, float q0, float q1, float q2, float q3, float rp,
    float& o0, float& o1, float& o2, float& o3)
{
    int beg = rowptr[nid], end = rowptr[nid + 1];
    float denom = 0.f, s0 = 0.f, s1 = 0.f, s2 = 0.f, s3 = 0.f;
    int i = beg;
    for (; i + 2 <= end; i += 2) {
        const unsigned* rA = kv + (size_t)srcs[i] * 128;
        const unsigned* rB = kv + (size_t)srcs[i + 1] * 128;
        uint2 kA = *(const uint2*)(rA + j * 2), kB = *(const uint2*)(rB + j * 2);
        uint2 vA = *(const uint2*)(rA + 64 + j * 2), vB = *(const uint2*)(rB + 64 + j * 2);
        float a0, a1, a2, a3, b0, b1, b2, b3;
        unpack2(kA.x, a0, a1); unpack2(kA.y, a2, a3);
        unpack2(kB.x, b0, b1); unpack2(kB.y, b2, b3);
        float dpA = a0 * q0 + a1 * q1 + a2 * q2 + a3 * q3;
        float dpB = b0 * q0 + b1 * q1 + b2 * q2 + b3 * q3;
        dpA += __shfl_xor(dpA, 1, 8); dpB += __shfl_xor(dpB, 1, 8);
        dpA += __shfl_xor(dpA, 2, 8); dpB += __shfl_xor(dpB, 2, 8);
        dpA += __shfl_xor(dpA, 4, 8); dpB += __shfl_xor(dpB, 4, 8);
        float wA = __expf(dpA * rp), wB = __expf(dpB * rp);
        unpack2(vA.x, a0, a1); unpack2(vA.y, a2, a3);
        unpack2(vB.x, b0, b1); unpack2(vB.y, b2, b3);
        denom += wA + wB;
        s0 += wA * a0 + wB * b0; s1 += wA * a1 + wB * b1;
        s2 += wA * a2 + wB * b2; s3 += wA * a3 + wB * b3;
    }
    if (i < end) {
        const unsigned* rA = kv + (size_t)srcs[i] * 128;
        uint2 kA = *(const uint2*)(rA + j * 2);
        uint2 vA = *(const uint2*)(rA + 64 + j * 2);
        float a0, a1, a2, a3;
        unpack2(kA.x, a0, a1); unpack2(kA.y, a2, a3);
        float dp = a0 * q0 + a1 * q1 + a2 * q2 + a3 * q3;
        dp += __shfl_xor(dp, 1, 8);
        dp += __shfl_xor(dp, 2, 8);
        dp += __shfl_xor(dp, 4, 8);
        float w = __expf(dp * rp);
        unpack2(vA.x, a0, a1); unpack2(vA.y, a2, a3);
        denom += w;
        s0 += w * a0; s1 += w * a1; s2 += w * a2; s3 += w * a3;
    }
    float r = 1.0f / (denom + 1e-16f);
    o0 += s0 * r; o1 += s1 * r; o2 += s2 * r; o3 += s3 * r;
}

// ---------- visit-dst edges: relations 0 and 2 merged ----------
__global__ __launch_bounds__(256) void edge_vis(
    const int* __restrict__ rp0, const int* __restrict__ s0, const unsigned* __restrict__ kv0,
    const int* __restrict__ rp2, const int* __restrict__ s2, const unsigned* __restrict__ kv2,
    const unsigned* __restrict__ qv, const float* __restrict__ relPl,
    unsigned* __restrict__ agg, int Nd)
{
    int nid = (int)((blockIdx.x * 256u + threadIdx.x) >> 5);
    int j = threadIdx.x & 31;
    if (nid >= Nd) return;
    int head = j >> 3;
    uint2 q2 = *(const uint2*)(qv + (size_t)nid * 64 + j * 2);
    float q0, q1, qq2, q3;
    unpack2(q2.x, q0, q1); unpack2(q2.y, qq2, q3);
    float rpA = relPl[0 * H + head] * RSC;
    float rpB = relPl[2 * H + head] * RSC;
    float o0 = 0.f, o1 = 0.f, o2 = 0.f, o3 = 0.f;
    rel_accum32(rp0, s0, kv0, nid, j, q0, q1, qq2, q3, rpA, o0, o1, o2, o3);
    rel_accum32(rp2, s2, kv2, nid, j, q0, q1, qq2, q3, rpB, o0, o1, o2, o3);
    uint2 o; o.x = pack2(o0, o1); o.y = pack2(o2, o3);
    *(uint2*)(agg + (size_t)nid * 64 + j * 2) = o;
}

// ---------- code-dst edges: relation 1 ----------
__global__ __launch_bounds__(256) void edge_code(
    const int* __restrict__ rp1, const int* __restrict__ s1, const unsigned* __restrict__ kv1,
    const unsigned* __restrict__ qv, const float* __restrict__ relPh,
    unsigned* __restrict__ agg, int Nd)
{
    int nid = (int)((blockIdx.x * 256u + threadIdx.x) >> 5);
    int j = threadIdx.x & 31;
    if (nid >= Nd) return;
    int head = j >> 3;
    uint2 q2 = *(const uint2*)(qv + (size_t)nid * 64 + j * 2);
    float q0, q1, qq2, q3;
    unpack2(q2.x, q0, q1); unpack2(q2.y, qq2, q3);
    float rp = relPh[head] * RSC;
    float o0 = 0.f, o1 = 0.f, o2 = 0.f, o3 = 0.f;
    rel_accum32(rp1, s1, kv1, nid, j, q0, q1, qq2, q3, rp, o0, o1, o2, o3);
    uint2 o; o.x = pack2(o0, o1); o.y = pack2(o2, o3);
    *(uint2*)(agg + (size_t)nid * 64 + j * 2) = o;
}

// ---------- final: gather last visit per patient, @ linW + linb ----------
__global__ void final_lin(const ushort_t* __restrict__ xs0, const int* __restrict__ slices,
                          const float* __restrict__ Wl, const float* __restrict__ bl,
                          float* __restrict__ out)
{
    __shared__ float xr[C];
    int b = blockIdx.x, o = threadIdx.x;
    int row = slices[b + 1] - 1;
    xr[o] = bf2f(xs0[(size_t)row * C + o]);
    __syncthreads();
    float acc = bl[o];
    #pragma unroll 4
    for (int c = 0; c < C; ++c) acc += xr[c] * Wl[c * C + o];
    out[(size_t)b * C + o] = acc;
}

extern "C" void kernel_launch(void* const* d_in, const int* in_sizes, int n_in,
                              void* d_out, int out_size, void* d_ws, size_t ws_size,
                              hipStream_t stream)
{
    (void)n_in;
    const float* x_visit = (const float*)d_in[0];
    const float* x_code  = (const float*)d_in[1];
    const int* slices    = (const int*)d_in[5];
    const float* lin0_W  = (const float*)d_in[6];
    const float* lin0_b  = (const float*)d_in[7];
    const float* kW  = (const float*)d_in[8];
    const float* kb  = (const float*)d_in[9];
    const float* qW  = (const float*)d_in[10];
    const float* qb  = (const float*)d_in[11];
    const float* vW  = (const float*)d_in[12];
    const float* vb  = (const float*)d_in[13];
    const float* aW  = (const float*)d_in[14];
    const float* ab  = (const float*)d_in[15];
    const float* skip = (const float*)d_in[16];
    const float* relA = (const float*)d_in[17];
    const float* relM = (const float*)d_in[18];
    const float* relP = (const float*)d_in[19];
    const float* linW = (const float*)d_in[20];
    const float* linb = (const float*)d_in[21];

    const int NV = in_sizes[0] / C;
    const int NC = in_sizes[1] / C;
    const int NN = NV > NC ? NV : NC;
    const int B = in_sizes[5] - 1;

    const int* eptr[3] = {(const int*)d_in[2], (const int*)d_in[3], (const int*)d_in[4]};
    const int Ecnt[3] = {in_sizes[2] / 2, in_sizes[3] / 2, in_sizes[4] / 2};
    const int Ndrel[3] = {NV, NC, NV};

    // ---- workspace plan with aliased regions; must fit ws_size (~359.37 MB measured) ----
    size_t off = 0;
    auto AL = [&](size_t bytes) { size_t c = off; off += (bytes + 255) & ~(size_t)255; return c; };
    size_t o_xs0  = AL((size_t)NV * C * 2);       // 25.6M
    size_t o_xs1  = AL((size_t)NC * C * 2);       // 51.2M
    size_t o_q0   = AL((size_t)NV * C * 2);       // 25.6M
    size_t o_q1   = AL((size_t)NC * C * 2);       // 51.2M
    size_t o_aggV = AL((size_t)NV * C * 2);       // 25.6M
    size_t o_rp[3], o_srcs[3];
    for (int e = 0; e < 3; ++e) {
        o_rp[e]   = AL(((size_t)Ndrel[e] + 1) * 4);
        o_srcs[e] = AL((size_t)Ecnt[e] * 4);
    }
    size_t o_wp   = AL(((size_t)NN + 1) * 4);
    size_t o_part = AL(4096);
    size_t o_fw   = AL((size_t)12 * (CC + C) * 4);
    size_t o_wt   = AL((size_t)22 * CC * 2);
    size_t o_RA   = AL((size_t)NC * 2 * C * 2);   // 102.4M: kv0, later kv1
    size_t o_RB   = AL((size_t)NV * 2 * C * 2 > (size_t)NC * C * 2
                       ? (size_t)NV * 2 * C * 2 : (size_t)NC * C * 2);  // 51.2M: kv2, later aggC
    size_t total = off;

    if (ws_size < total) {
        float v = 30.0f + (float)((double)ws_size * 1e-9);
        diag_fill<<<(out_size + 255) / 256, 256, 0, stream>>>((float*)d_out, out_size, v);
        return;
    }

    char* base = (char*)d_ws;
    ushort_t* xs0  = (ushort_t*)(base + o_xs0);
    ushort_t* xs1  = (ushort_t*)(base + o_xs1);
    ushort_t* q0   = (ushort_t*)(base + o_q0);
    ushort_t* q1   = (ushort_t*)(base + o_q1);
    ushort_t* aggV = (ushort_t*)(base + o_aggV);
    int* rp_[3]; int* srcs_[3];
    for (int e = 0; e < 3; ++e) { rp_[e] = (int*)(base + o_rp[e]); srcs_[e] = (int*)(base + o_srcs[e]); }
    int* wp   = (int*)(base + o_wp);
    int* part = (int*)(base + o_part);
    float* fw = (float*)(base + o_fw);
    ushort_t* wt = (ushort_t*)(base + o_wt);
    ushort_t* kv0  = (ushort_t*)(base + o_RA);    // code-source (rel 0)
    ushort_t* kv1  = (ushort_t*)(base + o_RA);    // visit-source (rel 1), after edgeV
    ushort_t* kv2  = (ushort_t*)(base + o_RB);    // visit-source (rel 2)
    ushort_t* aggC = (ushort_t*)(base + o_RB);    // after edgeV/edgeC

    auto wt_q = [&](int l, int t) { return wt + (size_t)(2 + l * 2 + t) * CC; };
    auto wt_a = [&](int l, int t) { return wt + (size_t)(6 + l * 2 + t) * CC; };
    auto wt_f = [&](int le, int which) { return wt + (size_t)(10 + le * 2 + which) * CC; };
    auto fb   = [&](int le, int which) { return fw + (size_t)(le * 2 + which) * (CC + C) + CC; };

    // 1) weight prep
    fuse_weights<<<12, 256, 0, stream>>>(kW, kb, vW, vb, relA, relM, fw);
    trans_w<<<22, 256, 0, stream>>>(lin0_W, qW, aW, fw, wt);

    // 2) CSR build per relation
    for (int e = 0; e < 3; ++e) {
        int Nd = Ndrel[e], E = Ecnt[e];
        int nb = (Nd + SC - 1) / SC;
        hipMemsetAsync(wp, 0, (size_t)Nd * 4, stream);
        hist_k<<<(E + 255) / 256, 256, 0, stream>>>(eptr[e], E, wp);
        scan1<<<nb, 256, 0, stream>>>(wp, Nd, part);
        scan2<<<1, 64, 0, stream>>>(part, nb);
        scan3<<<nb, 256, 0, stream>>>(wp, Nd, part, rp_[e]);
        hipMemcpyAsync(wp, rp_[e], (size_t)Nd * 4, hipMemcpyDeviceToDevice, stream);
        scatter_k<<<(E + 255) / 256, 256, 0, stream>>>(eptr[e], E, wp, srcs_[e]);
    }

    const int tilesV = (NV + 63) / 64, tilesC = (NC + 63) / 64;
    unsigned gV = (unsigned)(((size_t)NV * 32 + 255) / 256);
    unsigned gC = (unsigned)(((size_t)NC * 32 + 255) / 256);

    for (int l = 0; l < 2; ++l) {
        // P_C: code update (or input proj) + chained {q1, kv0k, kv0v}
        {
            FusedArgs a = {};
            a.N = NC; a.nw = 3;
            a.j[0] = {wt_q(l, 1), qb + (l * 2 + 1) * C, q1, C};
            a.j[1] = {wt_f(l * 3 + 0, 0), fb(l * 3 + 0, 0), kv0, 2 * C};
            a.j[2] = {wt_f(l * 3 + 0, 1), fb(l * 3 + 0, 1), kv0 + C, 2 * C};
            if (l == 0) {
                a.X = x_code; a.W1 = wt + CC; a.b1 = lin0_b + C; a.Y1 = xs1;
                fusedProj<0, 0, 1><<<(unsigned)tilesC, 256, 0, stream>>>(a, a, tilesC);
            } else {
                a.X = aggC; a.W1 = wt_a(0, 1); a.b1 = ab + 1 * C; a.Y1 = xs1;
                a.Old = xs1; a.skipp = skip + 1;
                fusedProj<1, 1, 2><<<(unsigned)tilesC, 256, 0, stream>>>(a, a, tilesC);
            }
        }
        // P_V: visit update (or input proj) + chained {q0, kv2k, kv2v}
        {
            FusedArgs a = {};
            a.N = NV; a.nw = 3;
            a.j[0] = {wt_q(l, 0), qb + (l * 2 + 0) * C, q0, C};
            a.j[1] = {wt_f(l * 3 + 2, 0), fb(l * 3 + 2, 0), kv2, 2 * C};
            a.j[2] = {wt_f(l * 3 + 2, 1), fb(l * 3 + 2, 1), kv2 + C, 2 * C};
            if (l == 0) {
                a.X = x_visit; a.W1 = wt; a.b1 = lin0_b; a.Y1 = xs0;
                fusedProj<0, 0, 1><<<(unsigned)tilesV, 256, 0, stream>>>(a, a, tilesV);
            } else {
                a.X = aggV; a.W1 = wt_a(0, 0); a.b1 = ab + 0 * C; a.Y1 = xs0;
                a.Old = xs0; a.skipp = skip + 0;
                fusedProj<1, 1, 2><<<(unsigned)tilesV, 256, 0, stream>>>(a, a, tilesV);
            }
        }
        // edgeV: relations 0 (kv0) + 2 (kv2) -> aggV
        edge_vis<<<gV, 256, 0, stream>>>(
            rp_[0], srcs_[0], (const unsigned*)kv0,
            rp_[2], srcs_[2], (const unsigned*)kv2,
            (const unsigned*)q0, relP + (size_t)l * 3 * H, (unsigned*)aggV, NV);
        // kv1 projection from xs0 (into R_A, kv0 now dead)
        {
            const int le = l * 3 + 1;
            proj2<<<(unsigned)tilesV, 256, 0, stream>>>(
                xs0, wt_f(le, 0), fb(le, 0), wt_f(le, 1), fb(le, 1), kv1, kv1 + C, NV);
        }
        // edgeC: relation 1 (kv1) -> aggC (into R_B, kv2 now dead)
        edge_code<<<gC, 256, 0, stream>>>(
            rp_[1], srcs_[1], (const unsigned*)kv1,
            (const unsigned*)q1, relP + (size_t)(l * 3 + 1) * H, (unsigned*)aggC, NC);
    }

    // final update (layer-1) for both types in one launch (nw=0, no aliased writes)
    {
        FusedArgs aV = {}, aC = {};
        aV.X = aggV; aV.W1 = wt_a(1, 0); aV.b1 = ab + 2 * C; aV.Y1 = xs0;
        aV.Old = xs0; aV.skipp = skip + 2; aV.N = NV; aV.nw = 0;
        aC.X = aggC; aC.W1 = wt_a(1, 1); aC.b1 = ab + 3 * C; aC.Y1 = xs1;
        aC.Old = xs1; aC.skipp = skip + 3; aC.N = NC; aC.nw = 0;
        fusedProj<1, 1, 2><<<(unsigned)(tilesV + tilesC), 256, 0, stream>>>(aV, aC, tilesV);
    }

    // last visit per patient @ linW + linb
    final_lin<<<B, 128, 0, stream>>>(xs0, slices, linW, linb, (float*)d_out);
}